// Round 7
// baseline (462.345 us; speedup 1.0000x reference)
//
#include <hip/hip_runtime.h>

// Problem constants
#define B_  2
#define S_  2048
#define D_  2048
#define H_  16
#define HD_ 128

// 1/sqrt(128) * log2(e): fold softmax scale AND exp->exp2 conversion into Q
#define QSCALE 0.1275174319003887f

typedef __attribute__((ext_vector_type(4))) float  f32x4;
typedef __attribute__((ext_vector_type(8))) short  short8;
typedef __attribute__((ext_vector_type(8))) __bf16 bf16x8;
typedef __attribute__((ext_vector_type(4))) float  floatv4;
typedef __attribute__((ext_vector_type(4))) unsigned short ushortv4;

// fp32 -> bf16 bits, round-to-nearest-even
__device__ inline unsigned short f2bf(float f) {
  unsigned int u = __builtin_bit_cast(unsigned int, f);
  u += 0x7fffu + ((u >> 16) & 1u);
  return (unsigned short)(u >> 16);
}

// async global->LDS, 16B per lane. lds must be wave-uniform base; data lands at base + lane*16.
__device__ inline void gld16(void* lds, const void* g) {
  __builtin_amdgcn_global_load_lds(
      (const __attribute__((address_space(1))) unsigned int*)g,
      (__attribute__((address_space(3))) unsigned int*)lds, 16, 0, 0);
}

__device__ inline bf16x8 lds_frag_b(const void* p) {
  return __builtin_bit_cast(bf16x8, *(const short8*)p);
}

// ---------------------------------------------------------------- fused converts (x + 4 weights)
__global__ void cvt_all(const float* __restrict__ x,
                        const float* __restrict__ w0, const float* __restrict__ w1,
                        const float* __restrict__ w2, const float* __restrict__ w3,
                        unsigned short* __restrict__ xb,
                        unsigned short* __restrict__ wb0, unsigned short* __restrict__ wb1,
                        unsigned short* __restrict__ wb2, unsigned short* __restrict__ wb3) {
  int i = blockIdx.x * 256 + threadIdx.x;   // quad index, total 6291456
  const float* s; unsigned short* d; int off;
  if (i < 2097152) { s = x; d = xb; off = i; }
  else {
    int j = i - 2097152;
    int r = j >> 20; off = j & 1048575;
    s = (r == 0) ? w0 : (r == 1) ? w1 : (r == 2) ? w2 : w3;
    d = (r == 0) ? wb0 : (r == 1) ? wb1 : (r == 2) ? wb2 : wb3;
  }
  floatv4 v = ((const floatv4*)s)[off];
  ushortv4 o;
  o.x = f2bf(v.x); o.y = f2bf(v.y); o.z = f2bf(v.z); o.w = f2bf(v.w);
  ((ushortv4*)d)[off] = o;
}

// ---------------------------------------------------------------- 8-phase GEMM (NT), BM=256 BN=128 BK=64, 8 waves.
// R3-proven schedule (116 us, MfmaUtil 38.6%). R6's 4-phase merge regressed to 139 us (m196-class:
// coarse phase-split without fine interleave) -> reverted verbatim.
// Counted vmcnt: vmcnt(4)@P4 (buf1 tile landed), vmcnt(6)@P8 (buf0 tile landed). Never 0 in-loop.
// T2 swizzle (row&7)<<4; inverse-swizzled global src, linear LDS dest (rule #21).
// MODE 0: plain fp32 C (N=2048).
// MODE 1: QKV - coalesced fp32 stores: Q->CQ (B,S,D), K->CK (B,S,D), V->v_out (B,H,S,HD) direct.
template<int MI0, int NJ0>
__device__ inline void quad_mm(f32x4 (&acc)[4][4], const bf16x8 (&af)[2][2], const bf16x8 (&bf)[2][2]) {
#pragma unroll
  for (int mi = 0; mi < 2; ++mi)
#pragma unroll
    for (int nj = 0; nj < 2; ++nj)
#pragma unroll
      for (int ks = 0; ks < 2; ++ks)
        acc[MI0 + mi][NJ0 + nj] =
            __builtin_amdgcn_mfma_f32_16x16x32_bf16(af[mi][ks], bf[nj][ks], acc[MI0 + mi][NJ0 + nj], 0, 0, 0);
}

// stage one 8KB chunk (64 rows x 128B): global row stride 4096B, per-thread offset thrOff pre-swizzled
__device__ inline void stage(char* ldsbuf, int chunk, const char* gtile, int w, long thrOff) {
  gld16(ldsbuf + chunk * 8192 + w * 1024, gtile + (long)chunk * 64 * 4096 + thrOff);
}

#define RDF(dst, buf, baserow)                                                          \
  do {                                                                                  \
    int _r0 = (baserow);                                                                \
    _Pragma("unroll") for (int _ii = 0; _ii < 2; ++_ii) {                               \
      int _row = _r0 + _ii * 16;                                                        \
      _Pragma("unroll") for (int _ks = 0; _ks < 2; ++_ks)                               \
          dst[_ii][_ks] = lds_frag_b((buf) + _row * 128 + ((_ks * 64 + quad * 16) ^ xsw)); \
    }                                                                                   \
  } while (0)

#define GBAR() __builtin_amdgcn_s_barrier()
#define LGK0()                                                 \
  do {                                                         \
    asm volatile("s_waitcnt lgkmcnt(0)" ::: "memory");         \
    __builtin_amdgcn_sched_barrier(0);                         \
  } while (0)

template<int MODE>
__global__ __launch_bounds__(512, 1)
void gemm8p(const unsigned short* __restrict__ A,
            const unsigned short* __restrict__ W,
            const float* __restrict__ b0, const float* __restrict__ b1, const float* __restrict__ b2,
            float* __restrict__ CQ,      // MODE0: C. MODE1: Q fp32 (B,S,D)
            float* __restrict__ CK,      // MODE1: K fp32 (B,S,D)
            float* __restrict__ v_out,   // MODE1: V fp32 (B,H,S,HD)
            int nbx) {
  __shared__ __attribute__((aligned(16))) char smem[98304];  // As0|As1 (32K each), Bs0|Bs1 (16K each)
  char* As0 = smem;
  char* As1 = smem + 32768;
  char* Bs0 = smem + 65536;
  char* Bs1 = smem + 81920;

  const int t = threadIdx.x, w = t >> 6, lane = t & 63;
  const int quad = lane >> 4, l16 = lane & 15;
  const int wm = (w >> 1) * 64, wn = (w & 1) * 64;   // 4M x 2N waves, 64x64 per wave
  const int xsw = (l16 & 7) << 4;

  // XCD-bijective block decode (grid divisible by 8): contiguous wg chunk per XCD
  const int nwg = gridDim.x, q8 = nwg >> 3;
  const int wg = ((int)blockIdx.x & 7) * q8 + ((int)blockIdx.x >> 3);
  const int by = wg / nbx, bx = wg % nbx;
  const int m0 = by * 256, n0 = bx * 128;

  const char* Agl = (const char*)A + (size_t)m0 * 4096;   // row stride K*2 = 4096 B
  const char* Wgl = (const char*)W + (size_t)n0 * 4096;
  const int sr = t >> 3;
  const long thrOff = (long)sr * 4096 + (((t & 7) * 16) ^ ((sr & 7) << 4));  // inverse-swizzled src

  // prologue: prime tiles 0 (buf0) and 1 (buf1); oldest 6 = tile0
#pragma unroll
  for (int c = 0; c < 4; ++c) stage(As0, c, Agl, w, thrOff);
#pragma unroll
  for (int c = 0; c < 2; ++c) stage(Bs0, c, Wgl, w, thrOff);
#pragma unroll
  for (int c = 0; c < 4; ++c) stage(As1, c, Agl + 128, w, thrOff);
#pragma unroll
  for (int c = 0; c < 2; ++c) stage(Bs1, c, Wgl + 128, w, thrOff);
  asm volatile("s_waitcnt vmcnt(6)" ::: "memory");
  GBAR();

  f32x4 acc[4][4] = {};

  for (int it = 0; it < 16; ++it) {
    int s0 = 2 * it + 2; if (s0 >= 32) s0 -= 2;   // tail: benign identical restage
    int s1 = 2 * it + 3; if (s1 >= 32) s1 -= 2;
    const char* As0g = Agl + (long)s0 * 128;
    const char* Bs0g = Wgl + (long)s0 * 128;
    const char* As1g = Agl + (long)s1 * 128;
    const char* Bs1g = Wgl + (long)s1 * 128;
    bf16x8 a01[2][2], a23[2][2], b01[2][2], b23[2][2];

    // ---- P1: rd A01,B01 (buf0)                      | mfma Q(0,0)
    RDF(a01, As0, wm + l16);
    RDF(b01, Bs0, wn + l16);
    GBAR(); LGK0();
    __builtin_amdgcn_s_setprio(1); quad_mm<0, 0>(acc, a01, b01); __builtin_amdgcn_s_setprio(0);
    GBAR();
    // ---- P2: rd A23 (buf0)                          | mfma Q(2,0)
    RDF(a23, As0, wm + 32 + l16);
    GBAR(); LGK0();
    __builtin_amdgcn_s_setprio(1); quad_mm<2, 0>(acc, a23, b01); __builtin_amdgcn_s_setprio(0);
    GBAR();
    // ---- P3: rd B23 (buf0); stage buf0.A01 (free since P2) | mfma Q(0,2)
    RDF(b23, Bs0, wn + 32 + l16);
    stage(As0, 0, As0g, w, thrOff); stage(As0, 1, As0g, w, thrOff);
    GBAR(); LGK0();
    __builtin_amdgcn_s_setprio(1); quad_mm<0, 2>(acc, a01, b23); __builtin_amdgcn_s_setprio(0);
    GBAR();
    // ---- P4: stage buf0.A23                         | mfma Q(2,2) | vmcnt(4): buf1 tile landed
    stage(As0, 2, As0g, w, thrOff); stage(As0, 3, As0g, w, thrOff);
    GBAR(); LGK0();
    __builtin_amdgcn_s_setprio(1); quad_mm<2, 2>(acc, a23, b23); __builtin_amdgcn_s_setprio(0);
    asm volatile("s_waitcnt vmcnt(4)" ::: "memory");
    GBAR();
    // ---- P5: rd A01,B01 (buf1); stage buf0.B (free since P3) | mfma Q(0,0)
    RDF(a01, As1, wm + l16);
    RDF(b01, Bs1, wn + l16);
    stage(Bs0, 0, Bs0g, w, thrOff); stage(Bs0, 1, Bs0g, w, thrOff);
    GBAR(); LGK0();
    __builtin_amdgcn_s_setprio(1); quad_mm<0, 0>(acc, a01, b01); __builtin_amdgcn_s_setprio(0);
    GBAR();
    // ---- P6: rd A23 (buf1)                          | mfma Q(2,0)
    RDF(a23, As1, wm + 32 + l16);
    GBAR(); LGK0();
    __builtin_amdgcn_s_setprio(1); quad_mm<2, 0>(acc, a23, b01); __builtin_amdgcn_s_setprio(0);
    GBAR();
    // ---- P7: rd B23 (buf1); stage buf1.A01 (free since P6) | mfma Q(0,2)
    RDF(b23, Bs1, wn + 32 + l16);
    stage(As1, 0, As1g, w, thrOff); stage(As1, 1, As1g, w, thrOff);
    GBAR(); LGK0();
    __builtin_amdgcn_s_setprio(1); quad_mm<0, 2>(acc, a01, b23); __builtin_amdgcn_s_setprio(0);
    GBAR();
    // ---- P8: stage buf1.A23 + buf1.B (free since P7) | mfma Q(2,2) | vmcnt(6): buf0 tile landed
    stage(As1, 2, As1g, w, thrOff); stage(As1, 3, As1g, w, thrOff);
    stage(Bs1, 0, Bs1g, w, thrOff); stage(Bs1, 1, Bs1g, w, thrOff);
    GBAR(); LGK0();
    __builtin_amdgcn_s_setprio(1); quad_mm<2, 2>(acc, a23, b23); __builtin_amdgcn_s_setprio(0);
    asm volatile("s_waitcnt vmcnt(6)" ::: "memory");
    GBAR();
  }

  // drain tail restages before epilogue
  asm volatile("s_waitcnt vmcnt(0)" ::: "memory");

  // epilogue: C/D layout col=l16, row=quad*4+r. All stores fp32, 64B-per-16-lane coalesced.
  if constexpr (MODE == 1) {
#pragma unroll
    for (int nj = 0; nj < 4; ++nj) {
      int col = n0 + wn + nj * 16 + l16;            // 0..6143
      int sel = col >> 11;                          // 0=Q 1=K 2=V (uniform across wave)
      int cc  = col & 2047;
      const float* bp = (sel == 0) ? b0 : (sel == 1) ? b1 : b2;
      float bv = bp[cc];
#pragma unroll
      for (int mi = 0; mi < 4; ++mi)
#pragma unroll
        for (int r = 0; r < 4; ++r) {
          int row = m0 + wm + mi * 16 + quad * 4 + r;
          float v = acc[mi][nj][r] + bv;
          if (sel == 0) {
            CQ[(size_t)row * 2048 + cc] = v;
          } else if (sel == 1) {
            CK[(size_t)row * 2048 + cc] = v;
          } else {
            int s = row & 2047, bb = row >> 11;
            int hh = cc >> 7, d = cc & 127;
            v_out[((size_t)(bb * H_ + hh) * S_ + s) * HD_ + d] = v;
          }
        }
    }
  } else {
#pragma unroll
    for (int nj = 0; nj < 4; ++nj) {
      int col = n0 + wn + nj * 16 + l16;
      float bv = b0[col];
#pragma unroll
      for (int mi = 0; mi < 4; ++mi)
#pragma unroll
        for (int r = 0; r < 4; ++r) {
          int row = m0 + wm + mi * 16 + quad * 4 + r;
          CQ[(size_t)row * 2048 + col] = acc[mi][nj][r] + bv;
        }
    }
  }
}

// ---------------------------------------------------------------- RoPE: Q,K (B,S,D) fp32 -> (B,H,S,HD)
// Qa gets scale*log2e folded in (softmax runs in exp2 domain); Ka/k_out are unscaled.
__global__ void rope_kernel(const float* __restrict__ Qbuf,
                            const float* __restrict__ Kbuf,
                            const float* __restrict__ fc,
                            const float* __restrict__ fs,
                            unsigned short* __restrict__ Qa,
                            unsigned short* __restrict__ Ka,
                            float* __restrict__ k_out) {
  int idx = blockIdx.x * 256 + threadIdx.x;   // (b:1, s:11, h:4, i:6)
  int i = idx & 63;
  int h = (idx >> 6) & (H_ - 1);
  int s = (idx >> 10) & (S_ - 1);
  int b = idx >> 21;
  size_t src = ((size_t)(b * S_ + s)) * D_ + h * HD_ + 2 * i;
  float2 q = *(const float2*)(Qbuf + src);
  float2 k = *(const float2*)(Kbuf + src);
  float c = fc[s * 64 + i], sn = fs[s * 64 + i];
  float qor = q.x * c - q.y * sn, qoi = q.x * sn + q.y * c;
  float kor = k.x * c - k.y * sn, koi = k.x * sn + k.y * c;
  size_t dst = ((size_t)((b * H_ + h) * S_ + s)) * HD_ + 2 * i;
  *(unsigned int*)(Qa + dst) = (unsigned int)f2bf(qor * QSCALE) | ((unsigned int)f2bf(qoi * QSCALE) << 16);
  *(unsigned int*)(Ka + dst) = (unsigned int)f2bf(kor) | ((unsigned int)f2bf(koi) << 16);
  *(float2*)(k_out + dst) = make_float2(kor, koi);
}

// ---------------------------------------------------------------- V: v_out (B,H,S,HD) fp32 -> Vt (B,H,HD,S) bf16
__global__ void vtrans_kernel(const float* __restrict__ Vsrc,
                              unsigned short* __restrict__ Vt) {
  __shared__ float tile[64][33];
  int t = threadIdx.x;
  int s0 = blockIdx.x * 64, d0 = blockIdx.y * 32, bh = blockIdx.z;
#pragma unroll
  for (int rr = 0; rr < 8; ++rr) {
    int sl = rr * 8 + (t >> 5), dl = t & 31;
    tile[sl][dl] = Vsrc[((size_t)(bh * S_ + s0 + sl)) * HD_ + d0 + dl];
  }
  __syncthreads();
#pragma unroll
  for (int rr = 0; rr < 8; ++rr) {
    int dl = rr * 4 + (t >> 6), sl = t & 63;
    Vt[((size_t)(bh * HD_ + d0 + dl)) * S_ + s0 + sl] = f2bf(tile[sl][dl]);
  }
}

// ---------------------------------------------------------------- causal flash attention
// 64 q-rows/block (16/wave), paired subtiles {qs, 31-qs} per block for perfect causal balance
// (33 k-tiles each). 512 blocks -> 2 blocks/CU. Ks/Vs/Ps XOR-swizzled ((row&7)<<4).
// T13 (THR=0, bit-exact): skip alpha/rescale when no row's max grew (alpha==1.0 exactly).
__global__ __launch_bounds__(256, 2)
void attn_kernel(const unsigned short* __restrict__ Qa,
                 const unsigned short* __restrict__ Ka,
                 const unsigned short* __restrict__ Vt,
                 unsigned short* __restrict__ Oa) {
  __shared__ __attribute__((aligned(16))) unsigned short Ks[2][64 * 128]; // 32 KB [key][d] swz
  __shared__ __attribute__((aligned(16))) unsigned short Vs[128 * 64];    // 16 KB  [d][key] swz
  __shared__ __attribute__((aligned(16))) unsigned short Ps[4][16 * 64];  //  8 KB  per-wave P swz
  const int t = threadIdx.x, w = t >> 6, lane = t & 63;
  const int quad = lane >> 4, l16 = lane & 15;
  const int bid = blockIdx.x;                 // 512 blocks
  const int bh = (bid & 7) + 8 * (bid >> 7);
  const int p  = (bid >> 3) & 15;             // pair index 0..15
  const int b = bh >> 4, h = bh & 15;
  const unsigned short* Qp = Qa + (size_t)bh * S_ * HD_;
  const unsigned short* Kp = Ka + (size_t)bh * S_ * HD_;
  const unsigned short* Vp = Vt + (size_t)bh * HD_ * S_;
  const float NEGINF = -__builtin_inff();

  for (int part = 0; part < 2; ++part) {
    const int qs = part ? (31 - p) : p;       // 64-row q-subtile index
    const int q0 = qs * 64;
    const int ntmax = qs;                     // k-tiles 0..qs (64 keys each)

    __syncthreads();   // prior part's LDS reads fully done before restage

    // stage K[0]: LDS[row][cb] = K[row][cb ^ ((row&7)<<4)]
#pragma unroll
    for (int j = 0; j < 4; ++j) {
      int o = (t + 256 * j) * 16;
      int row = o >> 8, cb = (o & 255) ^ ((row & 7) << 4);
      gld16((char*)Ks[0] + w * 1024 + j * 4096, (const char*)(Kp + (size_t)row * HD_) + cb);
    }
    // Q fragments: loop-invariant, straight from global (16B/lane)
    bf16x8 qf[4];
#pragma unroll
    for (int kk = 0; kk < 4; ++kk)
      qf[kk] = *(const bf16x8*)(Qp + (size_t)(q0 + w * 16 + l16) * HD_ + kk * 32 + quad * 8);

    float m_i[4], l_i[4];
#pragma unroll
    for (int r = 0; r < 4; ++r) { m_i[r] = NEGINF; l_i[r] = 0.f; }
    f32x4 oacc[8] = {};
    int c = 0;

    for (int nt = 0; nt <= ntmax; ++nt) {
      __syncthreads();   // K[c] resident; drains K prefetch issued last iter

      // early-issue V[nt]: consumed only after softmax (mid barrier). 128B rows, swizzled src.
#pragma unroll
      for (int j = 0; j < 4; ++j) {
        int o = (t + 256 * j) * 16;
        int vrow = o >> 7, vcb = (o & 127) ^ ((vrow & 7) << 4);
        gld16((char*)Vs + w * 1024 + j * 4096,
              (const char*)(Vp + (size_t)vrow * S_ + nt * 64) + vcb);
      }

      // --- S = Q K^T: wave's 16 q-rows x 64 keys (log2 domain)
      f32x4 sacc[4] = {};
      const char* Kc = (const char*)Ks[c];
#pragma unroll
      for (int j = 0; j < 4; ++j) {
        int krow = j * 16 + l16;
        const char* kbase = Kc + krow * 256;
        int ksw = (krow & 7) << 4;
#pragma unroll
        for (int kk = 0; kk < 4; ++kk) {
          bf16x8 kf = lds_frag_b(kbase + ((kk * 64 + quad * 16) ^ ksw));
          sacc[j] = __builtin_amdgcn_mfma_f32_16x16x32_bf16(qf[kk], kf, sacc[j], 0, 0, 0);
        }
      }

      // --- causal mask (diagonal tile only) + online softmax (exp2 domain)
      const bool dotail = (nt == ntmax);
      float rowmax[4], rowsum[4];
#pragma unroll
      for (int r = 0; r < 4; ++r) rowmax[r] = NEGINF;
#pragma unroll
      for (int j = 0; j < 4; ++j) {
        int scol = nt * 64 + j * 16 + l16;
#pragma unroll
        for (int r = 0; r < 4; ++r) {
          float v = sacc[j][r];
          if (dotail && scol > q0 + w * 16 + quad * 4 + r) v = NEGINF;
          sacc[j][r] = v;
          rowmax[r] = fmaxf(rowmax[r], v);
        }
      }
#pragma unroll
      for (int off = 1; off < 16; off <<= 1)
#pragma unroll
        for (int r = 0; r < 4; ++r)
          rowmax[r] = fmaxf(rowmax[r], __shfl_xor(rowmax[r], off));

      // T13 defer-rescale (THR=0, bit-exact): if no row grew, alpha==1.0 -> skip rescale entirely
      bool grow = false;
#pragma unroll
      for (int r = 0; r < 4; ++r) grow = grow || (rowmax[r] > m_i[r]);
      if (__any(grow)) {
        float alpha[4];
#pragma unroll
        for (int r = 0; r < 4; ++r) {
          float mnew = fmaxf(m_i[r], rowmax[r]);
          alpha[r] = __builtin_amdgcn_exp2f(m_i[r] - mnew);   // first tile: exp2(-inf)=0
          m_i[r] = mnew;
          l_i[r] *= alpha[r];
        }
#pragma unroll
        for (int f = 0; f < 8; ++f)
#pragma unroll
          for (int r = 0; r < 4; ++r) oacc[f][r] *= alpha[r];
      }
#pragma unroll
      for (int r = 0; r < 4; ++r) rowsum[r] = 0.f;
#pragma unroll
      for (int j = 0; j < 4; ++j)
#pragma unroll
        for (int r = 0; r < 4; ++r) {
          float e = __builtin_amdgcn_exp2f(sacc[j][r] - m_i[r]);  // masked: exp2(-inf)=0
          sacc[j][r] = e;
          rowsum[r] += e;
        }
#pragma unroll
      for (int off = 1; off < 16; off <<= 1)
#pragma unroll
        for (int r = 0; r < 4; ++r)
          rowsum[r] += __shfl_xor(rowsum[r], off);
#pragma unroll
      for (int r = 0; r < 4; ++r) l_i[r] += rowsum[r];

      __syncthreads();   // V[nt] resident (drain covered by QK+softmax work)

      // prefetch K[nt+1] AFTER mid barrier: drained at NEXT top barrier (covered by PV)
      if (nt < ntmax) {
#pragma unroll
        for (int j = 0; j < 4; ++j) {
          int o = (t + 256 * j) * 16;
          int row = o >> 8, cb = (o & 255) ^ ((row & 7) << 4);
          gld16((char*)Ks[c ^ 1] + w * 1024 + j * 4096,
                (const char*)(Kp + (size_t)((nt + 1) * 64 + row) * HD_) + cb);
        }
      }

      // --- P: C-layout regs -> per-wave LDS (bf16, swizzled)
      char* Pw = (char*)&Ps[w][0];
#pragma unroll
      for (int j = 0; j < 4; ++j)
#pragma unroll
        for (int r = 0; r < 4; ++r) {
          int prow = quad * 4 + r;
          *(unsigned short*)(Pw + prow * 128 + ((2 * (j * 16 + l16)) ^ ((prow & 7) << 4))) = f2bf(sacc[j][r]);
        }
      asm volatile("s_waitcnt lgkmcnt(0)" ::: "memory");  // per-wave RAW on Ps

      // --- O += P V  (2 k-steps over 64 keys x 8 d-fragments)
      const char* Vb = (const char*)Vs;
      int psw = (l16 & 7) << 4;
#pragma unroll
      for (int s2 = 0; s2 < 2; ++s2) {
        bf16x8 pf = lds_frag_b(Pw + l16 * 128 + ((s2 * 64 + quad * 16) ^ psw));
#pragma unroll
        for (int f = 0; f < 8; ++f) {
          int vrow = f * 16 + l16;
          bf16x8 vf = lds_frag_b(Vb + vrow * 128 + ((s2 * 64 + quad * 16) ^ ((vrow & 7) << 4)));
          oacc[f] = __builtin_amdgcn_mfma_f32_16x16x32_bf16(pf, vf, oacc[f], 0, 0, 0);
        }
      }
      c ^= 1;
    }

    // epilogue: O / l -> bf16 (B,S,D)
    float invl[4];
#pragma unroll
    for (int r = 0; r < 4; ++r) invl[r] = 1.f / l_i[r];
#pragma unroll
    for (int f = 0; f < 8; ++f)
#pragma unroll
      for (int r = 0; r < 4; ++r) {
        int srow = q0 + w * 16 + quad * 4 + r;
        int d = f * 16 + l16;
        Oa[((size_t)(b * S_ + srow)) * D_ + h * HD_ + d] = f2bf(oacc[f][r] * invl[r]);
      }
  }
}

// ----------------------------------------------------------------
extern "C" void kernel_launch(void* const* d_in, const int* in_sizes, int n_in,
                              void* d_out, int out_size, void* d_ws, size_t ws_size,
                              hipStream_t stream) {
  const float* x    = (const float*)d_in[0];
  const float* wq_w = (const float*)d_in[1];
  const float* wq_b = (const float*)d_in[2];
  const float* wk_w = (const float*)d_in[3];
  const float* wk_b = (const float*)d_in[4];
  const float* wv_w = (const float*)d_in[5];
  const float* wv_b = (const float*)d_in[6];
  const float* wo_w = (const float*)d_in[7];
  const float* wo_b = (const float*)d_in[8];
  const float* fc   = (const float*)d_in[9];
  const float* fs   = (const float*)d_in[10];

  float* out = (float*)d_out;
  const size_t BSD = (size_t)B_ * S_ * D_;   // 8388608
  float* k_out = out + BSD;
  float* v_out = out + 2 * BSD;

  // workspace layout
  char* ws = (char*)d_ws;
  unsigned short* xb   = (unsigned short*)(ws);              // x bf16          16.78 MB
  unsigned short* wqb  = (unsigned short*)(ws + 16777216);   // wq bf16          8.39 MB (wq|wk|wv contiguous)
  unsigned short* wkb  = (unsigned short*)(ws + 25165824);
  unsigned short* wvb  = (unsigned short*)(ws + 33554432);
  unsigned short* wob  = (unsigned short*)(ws + 41943040);
  float*          Kbuf = (float*)(ws + 50331648);            // K fp32 (B,S,D)  33.55 MB
  unsigned short* Qat  = (unsigned short*)(ws + 83886080);   // Q roped bf16 (B,H,S,HD), pre-scaled
  unsigned short* Kat  = (unsigned short*)(ws + 100663296);  // K roped bf16 (B,H,S,HD)
  unsigned short* Vt   = (unsigned short*)(ws + 117440512);  // V bf16 (B,H,HD,S)
  unsigned short* Ab   = (unsigned short*)(ws + 134217728);  // attn out bf16 (B,S,D)

  // fp32 Q intermediate borrows d_out (overwritten by final out-projection)
  float* Qbuf = out;

  cvt_all<<<24576, 256, 0, stream>>>(x, wq_w, wk_w, wv_w, wo_w, xb, wqb, wkb, wvb, wob);

  // fused QKV GEMM (N=6144): 768 blocks = 3 exact CU rounds.
  // Q->Qbuf fp32, K->Kbuf fp32 (coalesced (B,S,D)); V->v_out fp32 (B,H,S,HD) direct.
  gemm8p<1><<<dim3(768), 512, 0, stream>>>(xb, wqb, wq_b, wk_b, wv_b,
                                           Qbuf, Kbuf, v_out, 48);

  rope_kernel<<<16384, 256, 0, stream>>>(Qbuf, Kbuf, fc, fs, Qat, Kat, k_out);
  vtrans_kernel<<<dim3(32, 4, 32), 256, 0, stream>>>(v_out, Vt);
  attn_kernel<<<512, 256, 0, stream>>>(Qat, Kat, Vt, Ab);

  // output projection: 256 blocks = 1 exact CU round
  gemm8p<0><<<dim3(256), 512, 0, stream>>>(Ab, wob, wo_b, nullptr, nullptr,
                                           out, nullptr, nullptr, 16);
}

// Round 8
// 455.839 us; speedup vs baseline: 1.0143x; 1.0143x over previous
//
#include <hip/hip_runtime.h>

// Problem constants
#define B_  2
#define S_  2048
#define D_  2048
#define H_  16
#define HD_ 128

// 1/sqrt(128) * log2(e): fold softmax scale AND exp->exp2 conversion into Q
#define QSCALE 0.1275174319003887f

typedef __attribute__((ext_vector_type(4))) float  f32x4;
typedef __attribute__((ext_vector_type(8))) short  short8;
typedef __attribute__((ext_vector_type(8))) __bf16 bf16x8;
typedef __attribute__((ext_vector_type(4))) float  floatv4;
typedef __attribute__((ext_vector_type(4))) unsigned short ushortv4;

// fp32 -> bf16 bits, round-to-nearest-even
__device__ inline unsigned short f2bf(float f) {
  unsigned int u = __builtin_bit_cast(unsigned int, f);
  u += 0x7fffu + ((u >> 16) & 1u);
  return (unsigned short)(u >> 16);
}

// async global->LDS, 16B per lane. lds must be wave-uniform base; data lands at base + lane*16.
__device__ inline void gld16(void* lds, const void* g) {
  __builtin_amdgcn_global_load_lds(
      (const __attribute__((address_space(1))) unsigned int*)g,
      (__attribute__((address_space(3))) unsigned int*)lds, 16, 0, 0);
}

__device__ inline bf16x8 lds_frag_b(const void* p) {
  return __builtin_bit_cast(bf16x8, *(const short8*)p);
}

// ---------------------------------------------------------------- fused converts (x + 4 weights)
__global__ void cvt_all(const float* __restrict__ x,
                        const float* __restrict__ w0, const float* __restrict__ w1,
                        const float* __restrict__ w2, const float* __restrict__ w3,
                        unsigned short* __restrict__ xb,
                        unsigned short* __restrict__ wb0, unsigned short* __restrict__ wb1,
                        unsigned short* __restrict__ wb2, unsigned short* __restrict__ wb3) {
  int i = blockIdx.x * 256 + threadIdx.x;   // quad index, total 6291456
  const float* s; unsigned short* d; int off;
  if (i < 2097152) { s = x; d = xb; off = i; }
  else {
    int j = i - 2097152;
    int r = j >> 20; off = j & 1048575;
    s = (r == 0) ? w0 : (r == 1) ? w1 : (r == 2) ? w2 : w3;
    d = (r == 0) ? wb0 : (r == 1) ? wb1 : (r == 2) ? wb2 : wb3;
  }
  floatv4 v = ((const floatv4*)s)[off];
  ushortv4 o;
  o.x = f2bf(v.x); o.y = f2bf(v.y); o.z = f2bf(v.z); o.w = f2bf(v.w);
  ((ushortv4*)d)[off] = o;
}

// ---------------------------------------------------------------- 8-phase GEMM (NT), BM=256 BN=128 BK=64, 8 waves.
// R3-proven schedule (116-122 us, MfmaUtil 37-39%). 4-phase merge regressed (m196-class) - do not coarsen.
// Counted vmcnt: vmcnt(4)@P4 (buf1 tile landed), vmcnt(6)@P8 (buf0 tile landed). Never 0 in-loop.
// T2 swizzle (row&7)<<4; inverse-swizzled global src, linear LDS dest (rule #21).
// MODE 0: plain fp32 C (N=2048).
// MODE 1: QKV - coalesced fp32 stores: Q->CQ (B,S,D), K->CK (B,S,D), V->v_out (B,H,S,HD) direct.
template<int MI0, int NJ0>
__device__ inline void quad_mm(f32x4 (&acc)[4][4], const bf16x8 (&af)[2][2], const bf16x8 (&bf)[2][2]) {
#pragma unroll
  for (int mi = 0; mi < 2; ++mi)
#pragma unroll
    for (int nj = 0; nj < 2; ++nj)
#pragma unroll
      for (int ks = 0; ks < 2; ++ks)
        acc[MI0 + mi][NJ0 + nj] =
            __builtin_amdgcn_mfma_f32_16x16x32_bf16(af[mi][ks], bf[nj][ks], acc[MI0 + mi][NJ0 + nj], 0, 0, 0);
}

// stage one 8KB chunk (64 rows x 128B): global row stride 4096B, per-thread offset thrOff pre-swizzled
__device__ inline void stage(char* ldsbuf, int chunk, const char* gtile, int w, long thrOff) {
  gld16(ldsbuf + chunk * 8192 + w * 1024, gtile + (long)chunk * 64 * 4096 + thrOff);
}

#define RDF(dst, buf, baserow)                                                          \
  do {                                                                                  \
    int _r0 = (baserow);                                                                \
    _Pragma("unroll") for (int _ii = 0; _ii < 2; ++_ii) {                               \
      int _row = _r0 + _ii * 16;                                                        \
      _Pragma("unroll") for (int _ks = 0; _ks < 2; ++_ks)                               \
          dst[_ii][_ks] = lds_frag_b((buf) + _row * 128 + ((_ks * 64 + quad * 16) ^ xsw)); \
    }                                                                                   \
  } while (0)

#define GBAR() __builtin_amdgcn_s_barrier()
#define LGK0()                                                 \
  do {                                                         \
    asm volatile("s_waitcnt lgkmcnt(0)" ::: "memory");         \
    __builtin_amdgcn_sched_barrier(0);                         \
  } while (0)

template<int MODE>
__global__ __launch_bounds__(512, 1)
void gemm8p(const unsigned short* __restrict__ A,
            const unsigned short* __restrict__ W,
            const float* __restrict__ b0, const float* __restrict__ b1, const float* __restrict__ b2,
            float* __restrict__ CQ,      // MODE0: C. MODE1: Q fp32 (B,S,D)
            float* __restrict__ CK,      // MODE1: K fp32 (B,S,D)
            float* __restrict__ v_out,   // MODE1: V fp32 (B,H,S,HD)
            int nbx) {
  __shared__ __attribute__((aligned(16))) char smem[98304];  // As0|As1 (32K each), Bs0|Bs1 (16K each)
  char* As0 = smem;
  char* As1 = smem + 32768;
  char* Bs0 = smem + 65536;
  char* Bs1 = smem + 81920;

  const int t = threadIdx.x, w = t >> 6, lane = t & 63;
  const int quad = lane >> 4, l16 = lane & 15;
  const int wm = (w >> 1) * 64, wn = (w & 1) * 64;   // 4M x 2N waves, 64x64 per wave
  const int xsw = (l16 & 7) << 4;

  // XCD-bijective block decode (grid divisible by 8): contiguous wg chunk per XCD
  const int nwg = gridDim.x, q8 = nwg >> 3;
  const int wg = ((int)blockIdx.x & 7) * q8 + ((int)blockIdx.x >> 3);
  const int by = wg / nbx, bx = wg % nbx;
  const int m0 = by * 256, n0 = bx * 128;

  const char* Agl = (const char*)A + (size_t)m0 * 4096;   // row stride K*2 = 4096 B
  const char* Wgl = (const char*)W + (size_t)n0 * 4096;
  const int sr = t >> 3;
  const long thrOff = (long)sr * 4096 + (((t & 7) * 16) ^ ((sr & 7) << 4));  // inverse-swizzled src

  // prologue: prime tiles 0 (buf0) and 1 (buf1); oldest 6 = tile0
#pragma unroll
  for (int c = 0; c < 4; ++c) stage(As0, c, Agl, w, thrOff);
#pragma unroll
  for (int c = 0; c < 2; ++c) stage(Bs0, c, Wgl, w, thrOff);
#pragma unroll
  for (int c = 0; c < 4; ++c) stage(As1, c, Agl + 128, w, thrOff);
#pragma unroll
  for (int c = 0; c < 2; ++c) stage(Bs1, c, Wgl + 128, w, thrOff);
  asm volatile("s_waitcnt vmcnt(6)" ::: "memory");
  GBAR();

  f32x4 acc[4][4] = {};

  for (int it = 0; it < 16; ++it) {
    int s0 = 2 * it + 2; if (s0 >= 32) s0 -= 2;   // tail: benign identical restage
    int s1 = 2 * it + 3; if (s1 >= 32) s1 -= 2;
    const char* As0g = Agl + (long)s0 * 128;
    const char* Bs0g = Wgl + (long)s0 * 128;
    const char* As1g = Agl + (long)s1 * 128;
    const char* Bs1g = Wgl + (long)s1 * 128;
    bf16x8 a01[2][2], a23[2][2], b01[2][2], b23[2][2];

    // ---- P1: rd A01,B01 (buf0)                      | mfma Q(0,0)
    RDF(a01, As0, wm + l16);
    RDF(b01, Bs0, wn + l16);
    GBAR(); LGK0();
    __builtin_amdgcn_s_setprio(1); quad_mm<0, 0>(acc, a01, b01); __builtin_amdgcn_s_setprio(0);
    GBAR();
    // ---- P2: rd A23 (buf0)                          | mfma Q(2,0)
    RDF(a23, As0, wm + 32 + l16);
    GBAR(); LGK0();
    __builtin_amdgcn_s_setprio(1); quad_mm<2, 0>(acc, a23, b01); __builtin_amdgcn_s_setprio(0);
    GBAR();
    // ---- P3: rd B23 (buf0); stage buf0.A01 (free since P2) | mfma Q(0,2)
    RDF(b23, Bs0, wn + 32 + l16);
    stage(As0, 0, As0g, w, thrOff); stage(As0, 1, As0g, w, thrOff);
    GBAR(); LGK0();
    __builtin_amdgcn_s_setprio(1); quad_mm<0, 2>(acc, a01, b23); __builtin_amdgcn_s_setprio(0);
    GBAR();
    // ---- P4: stage buf0.A23                         | mfma Q(2,2) | vmcnt(4): buf1 tile landed
    stage(As0, 2, As0g, w, thrOff); stage(As0, 3, As0g, w, thrOff);
    GBAR(); LGK0();
    __builtin_amdgcn_s_setprio(1); quad_mm<2, 2>(acc, a23, b23); __builtin_amdgcn_s_setprio(0);
    asm volatile("s_waitcnt vmcnt(4)" ::: "memory");
    GBAR();
    // ---- P5: rd A01,B01 (buf1); stage buf0.B (free since P3) | mfma Q(0,0)
    RDF(a01, As1, wm + l16);
    RDF(b01, Bs1, wn + l16);
    stage(Bs0, 0, Bs0g, w, thrOff); stage(Bs0, 1, Bs0g, w, thrOff);
    GBAR(); LGK0();
    __builtin_amdgcn_s_setprio(1); quad_mm<0, 0>(acc, a01, b01); __builtin_amdgcn_s_setprio(0);
    GBAR();
    // ---- P6: rd A23 (buf1)                          | mfma Q(2,0)
    RDF(a23, As1, wm + 32 + l16);
    GBAR(); LGK0();
    __builtin_amdgcn_s_setprio(1); quad_mm<2, 0>(acc, a23, b01); __builtin_amdgcn_s_setprio(0);
    GBAR();
    // ---- P7: rd B23 (buf1); stage buf1.A01 (free since P6) | mfma Q(0,2)
    RDF(b23, Bs1, wn + 32 + l16);
    stage(As1, 0, As1g, w, thrOff); stage(As1, 1, As1g, w, thrOff);
    GBAR(); LGK0();
    __builtin_amdgcn_s_setprio(1); quad_mm<0, 2>(acc, a01, b23); __builtin_amdgcn_s_setprio(0);
    GBAR();
    // ---- P8: stage buf1.A23 + buf1.B (free since P7) | mfma Q(2,2) | vmcnt(6): buf0 tile landed
    stage(As1, 2, As1g, w, thrOff); stage(As1, 3, As1g, w, thrOff);
    stage(Bs1, 0, Bs1g, w, thrOff); stage(Bs1, 1, Bs1g, w, thrOff);
    GBAR(); LGK0();
    __builtin_amdgcn_s_setprio(1); quad_mm<2, 2>(acc, a23, b23); __builtin_amdgcn_s_setprio(0);
    asm volatile("s_waitcnt vmcnt(6)" ::: "memory");
    GBAR();
  }

  // drain tail restages before epilogue
  asm volatile("s_waitcnt vmcnt(0)" ::: "memory");

  // epilogue: C/D layout col=l16, row=quad*4+r. All stores fp32, 64B-per-16-lane coalesced.
  if constexpr (MODE == 1) {
#pragma unroll
    for (int nj = 0; nj < 4; ++nj) {
      int col = n0 + wn + nj * 16 + l16;            // 0..6143
      int sel = col >> 11;                          // 0=Q 1=K 2=V (uniform across wave)
      int cc  = col & 2047;
      const float* bp = (sel == 0) ? b0 : (sel == 1) ? b1 : b2;
      float bv = bp[cc];
#pragma unroll
      for (int mi = 0; mi < 4; ++mi)
#pragma unroll
        for (int r = 0; r < 4; ++r) {
          int row = m0 + wm + mi * 16 + quad * 4 + r;
          float v = acc[mi][nj][r] + bv;
          if (sel == 0) {
            CQ[(size_t)row * 2048 + cc] = v;
          } else if (sel == 1) {
            CK[(size_t)row * 2048 + cc] = v;
          } else {
            int s = row & 2047, bb = row >> 11;
            int hh = cc >> 7, d = cc & 127;
            v_out[((size_t)(bb * H_ + hh) * S_ + s) * HD_ + d] = v;
          }
        }
    }
  } else {
#pragma unroll
    for (int nj = 0; nj < 4; ++nj) {
      int col = n0 + wn + nj * 16 + l16;
      float bv = b0[col];
#pragma unroll
      for (int mi = 0; mi < 4; ++mi)
#pragma unroll
        for (int r = 0; r < 4; ++r) {
          int row = m0 + wm + mi * 16 + quad * 4 + r;
          CQ[(size_t)row * 2048 + col] = acc[mi][nj][r] + bv;
        }
    }
  }
}

// ---------------------------------------------------------------- fused RoPE + V-transpose (one launch)
// blocks [0,16384): RoPE  Q,K (B,S,D) fp32 -> (B,H,S,HD) bf16 (+k_out fp32)
// blocks [16384,20480): vtrans  v_out (B,H,S,HD) fp32 -> Vt (B,H,HD,S) bf16
__global__ void rope_vtrans(const float* __restrict__ Qbuf,
                            const float* __restrict__ Kbuf,
                            const float* __restrict__ fc,
                            const float* __restrict__ fs,
                            unsigned short* __restrict__ Qa,
                            unsigned short* __restrict__ Ka,
                            float* __restrict__ k_out,
                            const float* __restrict__ Vsrc,
                            unsigned short* __restrict__ Vt) {
  __shared__ float tile[64][33];
  int bx = blockIdx.x;
  int t = threadIdx.x;
  if (bx < 16384) {
    int idx = bx * 256 + t;   // (b:1, s:11, h:4, i:6)
    int i = idx & 63;
    int h = (idx >> 6) & (H_ - 1);
    int s = (idx >> 10) & (S_ - 1);
    int b = idx >> 21;
    size_t src = ((size_t)(b * S_ + s)) * D_ + h * HD_ + 2 * i;
    float2 q = *(const float2*)(Qbuf + src);
    float2 k = *(const float2*)(Kbuf + src);
    float c = fc[s * 64 + i], sn = fs[s * 64 + i];
    float qor = q.x * c - q.y * sn, qoi = q.x * sn + q.y * c;
    float kor = k.x * c - k.y * sn, koi = k.x * sn + k.y * c;
    size_t dst = ((size_t)((b * H_ + h) * S_ + s)) * HD_ + 2 * i;
    *(unsigned int*)(Qa + dst) = (unsigned int)f2bf(qor * QSCALE) | ((unsigned int)f2bf(qoi * QSCALE) << 16);
    *(unsigned int*)(Ka + dst) = (unsigned int)f2bf(kor) | ((unsigned int)f2bf(koi) << 16);
    *(float2*)(k_out + dst) = make_float2(kor, koi);
  } else {
    int v = bx - 16384;                    // 4096 blocks: (s0:32, d0:4, bh:32)
    int s0 = (v & 31) * 64, d0 = ((v >> 5) & 3) * 32, bh = v >> 7;
#pragma unroll
    for (int rr = 0; rr < 8; ++rr) {
      int sl = rr * 8 + (t >> 5), dl = t & 31;
      tile[sl][dl] = Vsrc[((size_t)(bh * S_ + s0 + sl)) * HD_ + d0 + dl];
    }
    __syncthreads();
#pragma unroll
    for (int rr = 0; rr < 8; ++rr) {
      int dl = rr * 4 + (t >> 6), sl = t & 63;
      Vt[((size_t)(bh * HD_ + d0 + dl)) * S_ + s0 + sl] = f2bf(tile[sl][dl]);
    }
  }
}

// ---------------------------------------------------------------- causal flash attention
// 64 q-rows/block (16/wave), paired subtiles {qs, 31-qs} per block for perfect causal balance
// (33 k-tiles each). 512 blocks -> 2 blocks/CU. Ks/Vs/Ps XOR-swizzled ((row&7)<<4).
// T13 reverted (R7: +13..40us regression, m253-class null). T5 setprio added (attn regime: m191 +4-7%).
__global__ __launch_bounds__(256, 2)
void attn_kernel(const unsigned short* __restrict__ Qa,
                 const unsigned short* __restrict__ Ka,
                 const unsigned short* __restrict__ Vt,
                 unsigned short* __restrict__ Oa) {
  __shared__ __attribute__((aligned(16))) unsigned short Ks[2][64 * 128]; // 32 KB [key][d] swz
  __shared__ __attribute__((aligned(16))) unsigned short Vs[128 * 64];    // 16 KB  [d][key] swz
  __shared__ __attribute__((aligned(16))) unsigned short Ps[4][16 * 64];  //  8 KB  per-wave P swz
  const int t = threadIdx.x, w = t >> 6, lane = t & 63;
  const int quad = lane >> 4, l16 = lane & 15;
  const int bid = blockIdx.x;                 // 512 blocks
  const int bh = (bid & 7) + 8 * (bid >> 7);
  const int p  = (bid >> 3) & 15;             // pair index 0..15
  const int b = bh >> 4, h = bh & 15;
  const unsigned short* Qp = Qa + (size_t)bh * S_ * HD_;
  const unsigned short* Kp = Ka + (size_t)bh * S_ * HD_;
  const unsigned short* Vp = Vt + (size_t)bh * HD_ * S_;
  const float NEGINF = -__builtin_inff();

  for (int part = 0; part < 2; ++part) {
    const int qs = part ? (31 - p) : p;       // 64-row q-subtile index
    const int q0 = qs * 64;
    const int ntmax = qs;                     // k-tiles 0..qs (64 keys each)

    __syncthreads();   // prior part's LDS reads fully done before restage

    // stage K[0]: LDS[row][cb] = K[row][cb ^ ((row&7)<<4)]
#pragma unroll
    for (int j = 0; j < 4; ++j) {
      int o = (t + 256 * j) * 16;
      int row = o >> 8, cb = (o & 255) ^ ((row & 7) << 4);
      gld16((char*)Ks[0] + w * 1024 + j * 4096, (const char*)(Kp + (size_t)row * HD_) + cb);
    }
    // Q fragments: loop-invariant, straight from global (16B/lane)
    bf16x8 qf[4];
#pragma unroll
    for (int kk = 0; kk < 4; ++kk)
      qf[kk] = *(const bf16x8*)(Qp + (size_t)(q0 + w * 16 + l16) * HD_ + kk * 32 + quad * 8);

    float m_i[4], l_i[4];
#pragma unroll
    for (int r = 0; r < 4; ++r) { m_i[r] = NEGINF; l_i[r] = 0.f; }
    f32x4 oacc[8] = {};
    int c = 0;

    for (int nt = 0; nt <= ntmax; ++nt) {
      __syncthreads();   // K[c] resident; drains K prefetch issued last iter

      // early-issue V[nt]: consumed only after softmax (mid barrier). 128B rows, swizzled src.
#pragma unroll
      for (int j = 0; j < 4; ++j) {
        int o = (t + 256 * j) * 16;
        int vrow = o >> 7, vcb = (o & 127) ^ ((vrow & 7) << 4);
        gld16((char*)Vs + w * 1024 + j * 4096,
              (const char*)(Vp + (size_t)vrow * S_ + nt * 64) + vcb);
      }

      // --- S = Q K^T: wave's 16 q-rows x 64 keys (log2 domain)
      f32x4 sacc[4] = {};
      const char* Kc = (const char*)Ks[c];
      __builtin_amdgcn_s_setprio(1);
#pragma unroll
      for (int j = 0; j < 4; ++j) {
        int krow = j * 16 + l16;
        const char* kbase = Kc + krow * 256;
        int ksw = (krow & 7) << 4;
#pragma unroll
        for (int kk = 0; kk < 4; ++kk) {
          bf16x8 kf = lds_frag_b(kbase + ((kk * 64 + quad * 16) ^ ksw));
          sacc[j] = __builtin_amdgcn_mfma_f32_16x16x32_bf16(qf[kk], kf, sacc[j], 0, 0, 0);
        }
      }
      __builtin_amdgcn_s_setprio(0);

      // --- causal mask (diagonal tile only) + online softmax (exp2 domain)
      const bool dotail = (nt == ntmax);
      float rowmax[4], alpha[4], rowsum[4];
#pragma unroll
      for (int r = 0; r < 4; ++r) rowmax[r] = NEGINF;
#pragma unroll
      for (int j = 0; j < 4; ++j) {
        int scol = nt * 64 + j * 16 + l16;
#pragma unroll
        for (int r = 0; r < 4; ++r) {
          float v = sacc[j][r];
          if (dotail && scol > q0 + w * 16 + quad * 4 + r) v = NEGINF;
          sacc[j][r] = v;
          rowmax[r] = fmaxf(rowmax[r], v);
        }
      }
#pragma unroll
      for (int off = 1; off < 16; off <<= 1)
#pragma unroll
        for (int r = 0; r < 4; ++r)
          rowmax[r] = fmaxf(rowmax[r], __shfl_xor(rowmax[r], off));
#pragma unroll
      for (int r = 0; r < 4; ++r) {
        float mnew = fmaxf(m_i[r], rowmax[r]);
        alpha[r] = __builtin_amdgcn_exp2f(m_i[r] - mnew);   // first tile: exp2(-inf)=0
        m_i[r] = mnew;
        rowsum[r] = 0.f;
      }
#pragma unroll
      for (int j = 0; j < 4; ++j)
#pragma unroll
        for (int r = 0; r < 4; ++r) {
          float e = __builtin_amdgcn_exp2f(sacc[j][r] - m_i[r]);  // masked: exp2(-inf)=0
          sacc[j][r] = e;
          rowsum[r] += e;
        }
#pragma unroll
      for (int off = 1; off < 16; off <<= 1)
#pragma unroll
        for (int r = 0; r < 4; ++r)
          rowsum[r] += __shfl_xor(rowsum[r], off);
#pragma unroll
      for (int r = 0; r < 4; ++r) l_i[r] = l_i[r] * alpha[r] + rowsum[r];
#pragma unroll
      for (int f = 0; f < 8; ++f)
#pragma unroll
        for (int r = 0; r < 4; ++r) oacc[f][r] *= alpha[r];

      __syncthreads();   // V[nt] resident (drain covered by QK+softmax work)

      // prefetch K[nt+1] AFTER mid barrier: drained at NEXT top barrier (covered by PV)
      if (nt < ntmax) {
#pragma unroll
        for (int j = 0; j < 4; ++j) {
          int o = (t + 256 * j) * 16;
          int row = o >> 8, cb = (o & 255) ^ ((row & 7) << 4);
          gld16((char*)Ks[c ^ 1] + w * 1024 + j * 4096,
                (const char*)(Kp + (size_t)((nt + 1) * 64 + row) * HD_) + cb);
        }
      }

      // --- P: C-layout regs -> per-wave LDS (bf16, swizzled)
      char* Pw = (char*)&Ps[w][0];
#pragma unroll
      for (int j = 0; j < 4; ++j)
#pragma unroll
        for (int r = 0; r < 4; ++r) {
          int prow = quad * 4 + r;
          *(unsigned short*)(Pw + prow * 128 + ((2 * (j * 16 + l16)) ^ ((prow & 7) << 4))) = f2bf(sacc[j][r]);
        }
      asm volatile("s_waitcnt lgkmcnt(0)" ::: "memory");  // per-wave RAW on Ps

      // --- O += P V  (2 k-steps over 64 keys x 8 d-fragments)
      const char* Vb = (const char*)Vs;
      int psw = (l16 & 7) << 4;
      __builtin_amdgcn_s_setprio(1);
#pragma unroll
      for (int s2 = 0; s2 < 2; ++s2) {
        bf16x8 pf = lds_frag_b(Pw + l16 * 128 + ((s2 * 64 + quad * 16) ^ psw));
#pragma unroll
        for (int f = 0; f < 8; ++f) {
          int vrow = f * 16 + l16;
          bf16x8 vf = lds_frag_b(Vb + vrow * 128 + ((s2 * 64 + quad * 16) ^ ((vrow & 7) << 4)));
          oacc[f] = __builtin_amdgcn_mfma_f32_16x16x32_bf16(pf, vf, oacc[f], 0, 0, 0);
        }
      }
      __builtin_amdgcn_s_setprio(0);
      c ^= 1;
    }

    // epilogue: O / l -> bf16 (B,S,D)
    float invl[4];
#pragma unroll
    for (int r = 0; r < 4; ++r) invl[r] = 1.f / l_i[r];
#pragma unroll
    for (int f = 0; f < 8; ++f)
#pragma unroll
      for (int r = 0; r < 4; ++r) {
        int srow = q0 + w * 16 + quad * 4 + r;
        int d = f * 16 + l16;
        Oa[((size_t)(b * S_ + srow)) * D_ + h * HD_ + d] = f2bf(oacc[f][r] * invl[r]);
      }
  }
}

// ----------------------------------------------------------------
extern "C" void kernel_launch(void* const* d_in, const int* in_sizes, int n_in,
                              void* d_out, int out_size, void* d_ws, size_t ws_size,
                              hipStream_t stream) {
  const float* x    = (const float*)d_in[0];
  const float* wq_w = (const float*)d_in[1];
  const float* wq_b = (const float*)d_in[2];
  const float* wk_w = (const float*)d_in[3];
  const float* wk_b = (const float*)d_in[4];
  const float* wv_w = (const float*)d_in[5];
  const float* wv_b = (const float*)d_in[6];
  const float* wo_w = (const float*)d_in[7];
  const float* wo_b = (const float*)d_in[8];
  const float* fc   = (const float*)d_in[9];
  const float* fs   = (const float*)d_in[10];

  float* out = (float*)d_out;
  const size_t BSD = (size_t)B_ * S_ * D_;   // 8388608
  float* k_out = out + BSD;
  float* v_out = out + 2 * BSD;

  // workspace layout
  char* ws = (char*)d_ws;
  unsigned short* xb   = (unsigned short*)(ws);              // x bf16          16.78 MB
  unsigned short* wqb  = (unsigned short*)(ws + 16777216);   // wq bf16          8.39 MB (wq|wk|wv contiguous)
  unsigned short* wkb  = (unsigned short*)(ws + 25165824);
  unsigned short* wvb  = (unsigned short*)(ws + 33554432);
  unsigned short* wob  = (unsigned short*)(ws + 41943040);
  float*          Kbuf = (float*)(ws + 50331648);            // K fp32 (B,S,D)  33.55 MB
  unsigned short* Qat  = (unsigned short*)(ws + 83886080);   // Q roped bf16 (B,H,S,HD), pre-scaled
  unsigned short* Kat  = (unsigned short*)(ws + 100663296);  // K roped bf16 (B,H,S,HD)
  unsigned short* Vt   = (unsigned short*)(ws + 117440512);  // V bf16 (B,H,HD,S)
  unsigned short* Ab   = (unsigned short*)(ws + 134217728);  // attn out bf16 (B,S,D)

  // fp32 Q intermediate borrows d_out (overwritten by final out-projection)
  float* Qbuf = out;

  cvt_all<<<24576, 256, 0, stream>>>(x, wq_w, wk_w, wv_w, wo_w, xb, wqb, wkb, wvb, wob);

  // fused QKV GEMM (N=6144): 768 blocks = 3 exact CU rounds.
  // Q->Qbuf fp32, K->Kbuf fp32 (coalesced (B,S,D)); V->v_out fp32 (B,H,S,HD) direct.
  gemm8p<1><<<dim3(768), 512, 0, stream>>>(xb, wqb, wq_b, wk_b, wv_b,
                                           Qbuf, Kbuf, v_out, 48);

  // fused RoPE + V-transpose: one launch (16384 rope blocks + 4096 vtrans blocks)
  rope_vtrans<<<20480, 256, 0, stream>>>(Qbuf, Kbuf, fc, fs, Qat, Kat, k_out, v_out, Vt);

  attn_kernel<<<512, 256, 0, stream>>>(Qat, Kat, Vt, Ab);

  // output projection: 256 blocks = 1 exact CU round
  gemm8p<0><<<dim3(256), 512, 0, stream>>>(Ab, wob, wo_b, nullptr, nullptr,
                                           out, nullptr, nullptr, 16);
}

// Round 9
// 453.873 us; speedup vs baseline: 1.0187x; 1.0043x over previous
//
#include <hip/hip_runtime.h>

// Problem constants
#define B_  2
#define S_  2048
#define D_  2048
#define H_  16
#define HD_ 128

// 1/sqrt(128) * log2(e): fold softmax scale AND exp->exp2 conversion into Q
#define QSCALE 0.1275174319003887f

typedef __attribute__((ext_vector_type(4))) float  f32x4;
typedef __attribute__((ext_vector_type(8))) short  short8;
typedef __attribute__((ext_vector_type(8))) __bf16 bf16x8;
typedef __attribute__((ext_vector_type(4))) float  floatv4;
typedef __attribute__((ext_vector_type(4))) unsigned short ushortv4;

// fp32 -> bf16 bits, round-to-nearest-even
__device__ inline unsigned short f2bf(float f) {
  unsigned int u = __builtin_bit_cast(unsigned int, f);
  u += 0x7fffu + ((u >> 16) & 1u);
  return (unsigned short)(u >> 16);
}

// async global->LDS, 16B per lane. lds must be wave-uniform base; data lands at base + lane*16.
__device__ inline void gld16(void* lds, const void* g) {
  __builtin_amdgcn_global_load_lds(
      (const __attribute__((address_space(1))) unsigned int*)g,
      (__attribute__((address_space(3))) unsigned int*)lds, 16, 0, 0);
}

__device__ inline bf16x8 lds_frag_b(const void* p) {
  return __builtin_bit_cast(bf16x8, *(const short8*)p);
}

// ---------------------------------------------------------------- fused converts (x + 4 weights)
__global__ void cvt_all(const float* __restrict__ x,
                        const float* __restrict__ w0, const float* __restrict__ w1,
                        const float* __restrict__ w2, const float* __restrict__ w3,
                        unsigned short* __restrict__ xb,
                        unsigned short* __restrict__ wb0, unsigned short* __restrict__ wb1,
                        unsigned short* __restrict__ wb2, unsigned short* __restrict__ wb3) {
  int i = blockIdx.x * 256 + threadIdx.x;   // quad index, total 6291456
  const float* s; unsigned short* d; int off;
  if (i < 2097152) { s = x; d = xb; off = i; }
  else {
    int j = i - 2097152;
    int r = j >> 20; off = j & 1048575;
    s = (r == 0) ? w0 : (r == 1) ? w1 : (r == 2) ? w2 : w3;
    d = (r == 0) ? wb0 : (r == 1) ? wb1 : (r == 2) ? wb2 : wb3;
  }
  floatv4 v = ((const floatv4*)s)[off];
  ushortv4 o;
  o.x = f2bf(v.x); o.y = f2bf(v.y); o.z = f2bf(v.z); o.w = f2bf(v.w);
  ((ushortv4*)d)[off] = o;
}

#define GBAR() __builtin_amdgcn_s_barrier()
#define LGK0()                                                 \
  do {                                                         \
    asm volatile("s_waitcnt lgkmcnt(0)" ::: "memory");         \
    __builtin_amdgcn_sched_barrier(0);                         \
  } while (0)

// stage one 8KB chunk (64 rows x 128B): global row stride 4096B, per-thread offset thrOff pre-swizzled
__device__ inline void stage(char* ldsbuf, int chunk, const char* gtile, int w, long thrOff) {
  gld16(ldsbuf + chunk * 8192 + w * 1024, gtile + (long)chunk * 64 * 4096 + thrOff);
}

#define RDF2(dst, buf, baserow)                                                          \
  do {                                                                                   \
    int _r0 = (baserow);                                                                 \
    _Pragma("unroll") for (int _ii = 0; _ii < 2; ++_ii) {                                \
      int _row = _r0 + _ii * 16;                                                         \
      _Pragma("unroll") for (int _ks = 0; _ks < 2; ++_ks)                                \
          dst[_ii][_ks] = lds_frag_b((buf) + _row * 128 + ((_ks * 64 + quad * 16) ^ xsw)); \
    }                                                                                    \
  } while (0)

#define RDF4(dst, buf, baserow)                                                          \
  do {                                                                                   \
    int _r0 = (baserow);                                                                 \
    _Pragma("unroll") for (int _ii = 0; _ii < 4; ++_ii) {                                \
      int _row = _r0 + _ii * 16;                                                         \
      _Pragma("unroll") for (int _ks = 0; _ks < 2; ++_ks)                                \
          dst[_ii][_ks] = lds_frag_b((buf) + _row * 128 + ((_ks * 64 + quad * 16) ^ xsw)); \
    }                                                                                    \
  } while (0)

// ---------------------------------------------------------------- 8-phase GEMM (NT), BM=256 BN=128, 8 waves, 64x64/wave.
// R3-proven schedule. Used for the output projection (256 blocks = 1 exact CU round).
template<int MI0, int NJ0>
__device__ inline void quad_mm(f32x4 (&acc)[4][4], const bf16x8 (&af)[2][2], const bf16x8 (&bf)[2][2]) {
#pragma unroll
  for (int mi = 0; mi < 2; ++mi)
#pragma unroll
    for (int nj = 0; nj < 2; ++nj)
#pragma unroll
      for (int ks = 0; ks < 2; ++ks)
        acc[MI0 + mi][NJ0 + nj] =
            __builtin_amdgcn_mfma_f32_16x16x32_bf16(af[mi][ks], bf[nj][ks], acc[MI0 + mi][NJ0 + nj], 0, 0, 0);
}

__global__ __launch_bounds__(512, 1)
void gemm8p(const unsigned short* __restrict__ A,
            const unsigned short* __restrict__ W,
            const float* __restrict__ b0,
            float* __restrict__ C0,
            int nbx) {
  __shared__ __attribute__((aligned(16))) char smem[98304];  // As0|As1 (32K each), Bs0|Bs1 (16K each)
  char* As0 = smem;
  char* As1 = smem + 32768;
  char* Bs0 = smem + 65536;
  char* Bs1 = smem + 81920;

  const int t = threadIdx.x, w = t >> 6, lane = t & 63;
  const int quad = lane >> 4, l16 = lane & 15;
  const int wm = (w >> 1) * 64, wn = (w & 1) * 64;   // 4M x 2N waves, 64x64 per wave
  const int xsw = (l16 & 7) << 4;

  const int nwg = gridDim.x, q8 = nwg >> 3;
  const int wg = ((int)blockIdx.x & 7) * q8 + ((int)blockIdx.x >> 3);
  const int by = wg / nbx, bx = wg % nbx;
  const int m0 = by * 256, n0 = bx * 128;

  const char* Agl = (const char*)A + (size_t)m0 * 4096;   // row stride K*2 = 4096 B
  const char* Wgl = (const char*)W + (size_t)n0 * 4096;
  const int sr = t >> 3;
  const long thrOff = (long)sr * 4096 + (((t & 7) * 16) ^ ((sr & 7) << 4));  // inverse-swizzled src

#pragma unroll
  for (int c = 0; c < 4; ++c) stage(As0, c, Agl, w, thrOff);
#pragma unroll
  for (int c = 0; c < 2; ++c) stage(Bs0, c, Wgl, w, thrOff);
#pragma unroll
  for (int c = 0; c < 4; ++c) stage(As1, c, Agl + 128, w, thrOff);
#pragma unroll
  for (int c = 0; c < 2; ++c) stage(Bs1, c, Wgl + 128, w, thrOff);
  asm volatile("s_waitcnt vmcnt(6)" ::: "memory");
  GBAR();

  f32x4 acc[4][4] = {};

  for (int it = 0; it < 16; ++it) {
    int s0 = 2 * it + 2; if (s0 >= 32) s0 -= 2;   // tail: benign identical restage
    int s1 = 2 * it + 3; if (s1 >= 32) s1 -= 2;
    const char* As0g = Agl + (long)s0 * 128;
    const char* Bs0g = Wgl + (long)s0 * 128;
    const char* As1g = Agl + (long)s1 * 128;
    const char* Bs1g = Wgl + (long)s1 * 128;
    bf16x8 a01[2][2], a23[2][2], b01[2][2], b23[2][2];

    // ---- P1
    RDF2(a01, As0, wm + l16);
    RDF2(b01, Bs0, wn + l16);
    GBAR(); LGK0();
    __builtin_amdgcn_s_setprio(1); quad_mm<0, 0>(acc, a01, b01); __builtin_amdgcn_s_setprio(0);
    GBAR();
    // ---- P2
    RDF2(a23, As0, wm + 32 + l16);
    GBAR(); LGK0();
    __builtin_amdgcn_s_setprio(1); quad_mm<2, 0>(acc, a23, b01); __builtin_amdgcn_s_setprio(0);
    GBAR();
    // ---- P3
    RDF2(b23, Bs0, wn + 32 + l16);
    stage(As0, 0, As0g, w, thrOff); stage(As0, 1, As0g, w, thrOff);
    GBAR(); LGK0();
    __builtin_amdgcn_s_setprio(1); quad_mm<0, 2>(acc, a01, b23); __builtin_amdgcn_s_setprio(0);
    GBAR();
    // ---- P4  | vmcnt(4): buf1 tile landed
    stage(As0, 2, As0g, w, thrOff); stage(As0, 3, As0g, w, thrOff);
    GBAR(); LGK0();
    __builtin_amdgcn_s_setprio(1); quad_mm<2, 2>(acc, a23, b23); __builtin_amdgcn_s_setprio(0);
    asm volatile("s_waitcnt vmcnt(4)" ::: "memory");
    GBAR();
    // ---- P5
    RDF2(a01, As1, wm + l16);
    RDF2(b01, Bs1, wn + l16);
    stage(Bs0, 0, Bs0g, w, thrOff); stage(Bs0, 1, Bs0g, w, thrOff);
    GBAR(); LGK0();
    __builtin_amdgcn_s_setprio(1); quad_mm<0, 0>(acc, a01, b01); __builtin_amdgcn_s_setprio(0);
    GBAR();
    // ---- P6
    RDF2(a23, As1, wm + 32 + l16);
    GBAR(); LGK0();
    __builtin_amdgcn_s_setprio(1); quad_mm<2, 0>(acc, a23, b01); __builtin_amdgcn_s_setprio(0);
    GBAR();
    // ---- P7
    RDF2(b23, Bs1, wn + 32 + l16);
    stage(As1, 0, As1g, w, thrOff); stage(As1, 1, As1g, w, thrOff);
    GBAR(); LGK0();
    __builtin_amdgcn_s_setprio(1); quad_mm<0, 2>(acc, a01, b23); __builtin_amdgcn_s_setprio(0);
    GBAR();
    // ---- P8  | vmcnt(6): buf0 tile landed
    stage(As1, 2, As1g, w, thrOff); stage(As1, 3, As1g, w, thrOff);
    stage(Bs1, 0, Bs1g, w, thrOff); stage(Bs1, 1, Bs1g, w, thrOff);
    GBAR(); LGK0();
    __builtin_amdgcn_s_setprio(1); quad_mm<2, 2>(acc, a23, b23); __builtin_amdgcn_s_setprio(0);
    asm volatile("s_waitcnt vmcnt(6)" ::: "memory");
    GBAR();
  }

  asm volatile("s_waitcnt vmcnt(0)" ::: "memory");

#pragma unroll
  for (int nj = 0; nj < 4; ++nj) {
    int col = n0 + wn + nj * 16 + l16;
    float bv = b0[col];
#pragma unroll
    for (int mi = 0; mi < 4; ++mi)
#pragma unroll
      for (int r = 0; r < 4; ++r) {
        int row = m0 + wm + mi * 16 + quad * 4 + r;
        C0[(size_t)row * 2048 + col] = acc[mi][nj][r] + bv;
      }
  }
}

// ---------------------------------------------------------------- 256x256 8-phase QKV GEMM (m201 geometry).
// BM=BN=256, BK=64, 8 waves (2M x 4N), per-wave 128x64 -> 16 MFMA/phase (2x the 256x128 kernel).
// Phase order per K-tile: Q00 -> Q01 -> Q11 -> Q10 so only one A-half is live at a time
// (peak live: acc 128 + a 32 + b0 16 + b1 16 ~= 212 VGPR).
// Stage ledger (8 chunk-stages per K-tile): A{0,2}@P2 (read P1), B{0-3}@P3 (read P1/P2),
// A{1,3}@P4 (read P3). vmcnt(8)@P4: drains other buffer's 8 -> buf1 resident for P5.
// vmcnt(8)@P8: drains buf0-next's 8. Prologue 16 stages -> vmcnt(8) = buf0 landed.
// Grid 384 = 1.5 CU rounds (quantization tax accepted for 2x phase density).
// Epilogue: Q->CQ fp32 (B,S,D), K->CK fp32 (B,S,D), V->v_out fp32 (B,H,S,HD); sel uniform per block.
template<int MH, int NH>
__device__ inline void mm16(f32x4 (&acc)[8][4], const bf16x8 (&af)[4][2], const bf16x8 (&bf)[2][2]) {
#pragma unroll
  for (int mi = 0; mi < 4; ++mi)
#pragma unroll
    for (int nj = 0; nj < 2; ++nj)
#pragma unroll
      for (int ks = 0; ks < 2; ++ks)
        acc[MH * 4 + mi][NH * 2 + nj] =
            __builtin_amdgcn_mfma_f32_16x16x32_bf16(af[mi][ks], bf[nj][ks], acc[MH * 4 + mi][NH * 2 + nj], 0, 0, 0);
}

__global__ __launch_bounds__(512, 1)
void gemm256_qkv(const unsigned short* __restrict__ A,
                 const unsigned short* __restrict__ W,
                 const float* __restrict__ b0, const float* __restrict__ b1, const float* __restrict__ b2,
                 float* __restrict__ CQ, float* __restrict__ CK, float* __restrict__ v_out) {
  __shared__ __attribute__((aligned(16))) char smem[131072];  // As0|As1|Bs0|Bs1, 32K each
  char* As0 = smem;
  char* As1 = smem + 32768;
  char* Bs0 = smem + 65536;
  char* Bs1 = smem + 98304;

  const int t = threadIdx.x, w = t >> 6, lane = t & 63;
  const int quad = lane >> 4, l16 = lane & 15;
  const int wm = (w >> 2) * 128, wn = (w & 3) * 64;   // 2M x 4N waves, 128x64 per wave
  const int xsw = (l16 & 7) << 4;

  // XCD-bijective decode: 384 blocks = 8 XCDs x 48
  const int wg = ((int)blockIdx.x & 7) * 48 + ((int)blockIdx.x >> 3);
  const int by = wg / 24, bx = wg % 24;
  const int m0 = by * 256, n0 = bx * 256;

  const char* Agl = (const char*)A + (size_t)m0 * 4096;
  const char* Wgl = (const char*)W + (size_t)n0 * 4096;
  const int sr = t >> 3;
  const long thrOff = (long)sr * 4096 + (((t & 7) * 16) ^ ((sr & 7) << 4));

  // prologue: buf0 (tile0: A 4 chunks + B 4 chunks), buf1 (tile1) -> 16 issues; vmcnt(8)=tile0 landed
#pragma unroll
  for (int c = 0; c < 4; ++c) stage(As0, c, Agl, w, thrOff);
#pragma unroll
  for (int c = 0; c < 4; ++c) stage(Bs0, c, Wgl, w, thrOff);
#pragma unroll
  for (int c = 0; c < 4; ++c) stage(As1, c, Agl + 128, w, thrOff);
#pragma unroll
  for (int c = 0; c < 4; ++c) stage(Bs1, c, Wgl + 128, w, thrOff);
  asm volatile("s_waitcnt vmcnt(8)" ::: "memory");
  GBAR();

  f32x4 acc[8][4] = {};

  for (int it = 0; it < 16; ++it) {
    int s0 = 2 * it + 2; if (s0 >= 32) s0 -= 2;   // tail: benign identical restage
    int s1 = 2 * it + 3; if (s1 >= 32) s1 -= 2;
    const char* As0g = Agl + (long)s0 * 128;
    const char* Bs0g = Wgl + (long)s0 * 128;
    const char* As1g = Agl + (long)s1 * 128;
    const char* Bs1g = Wgl + (long)s1 * 128;
    bf16x8 a[4][2], bl[2][2], bh[2][2];

    // ======== buf0 ========
    // ---- P1: rd A-half0 (chunks {0,2}), B-half0        | Q00
    RDF4(a, As0, wm + l16);
    RDF2(bl, Bs0, wn + l16);
    GBAR(); LGK0();
    __builtin_amdgcn_s_setprio(1); mm16<0, 0>(acc, a, bl); __builtin_amdgcn_s_setprio(0);
    GBAR();
    // ---- P2: rd B-half1; stage next A{0,2} (read P1)   | Q01
    RDF2(bh, Bs0, wn + 32 + l16);
    stage(As0, 0, As0g, w, thrOff); stage(As0, 2, As0g, w, thrOff);
    GBAR(); LGK0();
    __builtin_amdgcn_s_setprio(1); mm16<0, 1>(acc, a, bh); __builtin_amdgcn_s_setprio(0);
    GBAR();
    // ---- P3: rd A-half1 (chunks {1,3}); stage next B (read P1/P2) | Q11
    RDF4(a, As0, wm + 64 + l16);
    stage(Bs0, 0, Bs0g, w, thrOff); stage(Bs0, 1, Bs0g, w, thrOff);
    stage(Bs0, 2, Bs0g, w, thrOff); stage(Bs0, 3, Bs0g, w, thrOff);
    GBAR(); LGK0();
    __builtin_amdgcn_s_setprio(1); mm16<1, 1>(acc, a, bh); __builtin_amdgcn_s_setprio(0);
    GBAR();
    // ---- P4: stage next A{1,3} (read P3)               | Q10 | vmcnt(8): buf1 tile resident
    stage(As0, 1, As0g, w, thrOff); stage(As0, 3, As0g, w, thrOff);
    GBAR(); LGK0();
    __builtin_amdgcn_s_setprio(1); mm16<1, 0>(acc, a, bl); __builtin_amdgcn_s_setprio(0);
    asm volatile("s_waitcnt vmcnt(8)" ::: "memory");
    GBAR();
    // ======== buf1 ========
    // ---- P5
    RDF4(a, As1, wm + l16);
    RDF2(bl, Bs1, wn + l16);
    GBAR(); LGK0();
    __builtin_amdgcn_s_setprio(1); mm16<0, 0>(acc, a, bl); __builtin_amdgcn_s_setprio(0);
    GBAR();
    // ---- P6
    RDF2(bh, Bs1, wn + 32 + l16);
    stage(As1, 0, As1g, w, thrOff); stage(As1, 2, As1g, w, thrOff);
    GBAR(); LGK0();
    __builtin_amdgcn_s_setprio(1); mm16<0, 1>(acc, a, bh); __builtin_amdgcn_s_setprio(0);
    GBAR();
    // ---- P7
    RDF4(a, As1, wm + 64 + l16);
    stage(Bs1, 0, Bs1g, w, thrOff); stage(Bs1, 1, Bs1g, w, thrOff);
    stage(Bs1, 2, Bs1g, w, thrOff); stage(Bs1, 3, Bs1g, w, thrOff);
    GBAR(); LGK0();
    __builtin_amdgcn_s_setprio(1); mm16<1, 1>(acc, a, bh); __builtin_amdgcn_s_setprio(0);
    GBAR();
    // ---- P8 | vmcnt(8): buf0-next resident
    stage(As1, 1, As1g, w, thrOff); stage(As1, 3, As1g, w, thrOff);
    GBAR(); LGK0();
    __builtin_amdgcn_s_setprio(1); mm16<1, 0>(acc, a, bl); __builtin_amdgcn_s_setprio(0);
    asm volatile("s_waitcnt vmcnt(8)" ::: "memory");
    GBAR();
  }

  asm volatile("s_waitcnt vmcnt(0)" ::: "memory");

  // epilogue: sel uniform per block (n0 multiple of 256; 2048-boundaries are multiples of 256)
  const int sel = (n0 >> 11);
#pragma unroll
  for (int nf = 0; nf < 4; ++nf) {
    int col = n0 + wn + nf * 16 + l16;
    int cc  = col & 2047;
    const float* bp = (sel == 0) ? b0 : (sel == 1) ? b1 : b2;
    float bv = bp[cc];
#pragma unroll
    for (int mf = 0; mf < 8; ++mf)
#pragma unroll
      for (int r = 0; r < 4; ++r) {
        int row = m0 + wm + mf * 16 + quad * 4 + r;
        float v = acc[mf][nf][r] + bv;
        if (sel == 0) {
          CQ[(size_t)row * 2048 + cc] = v;
        } else if (sel == 1) {
          CK[(size_t)row * 2048 + cc] = v;
        } else {
          int s = row & 2047, bb = row >> 11;
          int hh = cc >> 7, d = cc & 127;
          v_out[((size_t)(bb * H_ + hh) * S_ + s) * HD_ + d] = v;
        }
      }
  }
}

// ---------------------------------------------------------------- fused RoPE + V-transpose (one launch)
// blocks [0,16384): RoPE  Q,K (B,S,D) fp32 -> (B,H,S,HD) bf16 (+k_out fp32)
// blocks [16384,20480): vtrans  v_out (B,H,S,HD) fp32 -> Vt (B,H,HD,S) bf16
__global__ void rope_vtrans(const float* __restrict__ Qbuf,
                            const float* __restrict__ Kbuf,
                            const float* __restrict__ fc,
                            const float* __restrict__ fs,
                            unsigned short* __restrict__ Qa,
                            unsigned short* __restrict__ Ka,
                            float* __restrict__ k_out,
                            const float* __restrict__ Vsrc,
                            unsigned short* __restrict__ Vt) {
  __shared__ float tile[64][33];
  int bx = blockIdx.x;
  int t = threadIdx.x;
  if (bx < 16384) {
    int idx = bx * 256 + t;   // (b:1, s:11, h:4, i:6)
    int i = idx & 63;
    int h = (idx >> 6) & (H_ - 1);
    int s = (idx >> 10) & (S_ - 1);
    int b = idx >> 21;
    size_t src = ((size_t)(b * S_ + s)) * D_ + h * HD_ + 2 * i;
    float2 q = *(const float2*)(Qbuf + src);
    float2 k = *(const float2*)(Kbuf + src);
    float c = fc[s * 64 + i], sn = fs[s * 64 + i];
    float qor = q.x * c - q.y * sn, qoi = q.x * sn + q.y * c;
    float kor = k.x * c - k.y * sn, koi = k.x * sn + k.y * c;
    size_t dst = ((size_t)((b * H_ + h) * S_ + s)) * HD_ + 2 * i;
    *(unsigned int*)(Qa + dst) = (unsigned int)f2bf(qor * QSCALE) | ((unsigned int)f2bf(qoi * QSCALE) << 16);
    *(unsigned int*)(Ka + dst) = (unsigned int)f2bf(kor) | ((unsigned int)f2bf(koi) << 16);
    *(float2*)(k_out + dst) = make_float2(kor, koi);
  } else {
    int v = bx - 16384;                    // 4096 blocks: (s0:32, d0:4, bh:32)
    int s0 = (v & 31) * 64, d0 = ((v >> 5) & 3) * 32, bh = v >> 7;
#pragma unroll
    for (int rr = 0; rr < 8; ++rr) {
      int sl = rr * 8 + (t >> 5), dl = t & 31;
      tile[sl][dl] = Vsrc[((size_t)(bh * S_ + s0 + sl)) * HD_ + d0 + dl];
    }
    __syncthreads();
#pragma unroll
    for (int rr = 0; rr < 8; ++rr) {
      int dl = rr * 4 + (t >> 6), sl = t & 63;
      Vt[((size_t)(bh * HD_ + d0 + dl)) * S_ + s0 + sl] = f2bf(tile[sl][dl]);
    }
  }
}

// ---------------------------------------------------------------- causal flash attention
// 64 q-rows/block (16/wave), paired subtiles {qs, 31-qs} per block for perfect causal balance
// (33 k-tiles each). 512 blocks -> 2 blocks/CU. Ks/Vs/Ps XOR-swizzled ((row&7)<<4).
// setprio REVERTED (R8: lockstep 4-wave block + 2 blocks/CU -> starves co-resident block, ~+35us).
__global__ __launch_bounds__(256, 2)
void attn_kernel(const unsigned short* __restrict__ Qa,
                 const unsigned short* __restrict__ Ka,
                 const unsigned short* __restrict__ Vt,
                 unsigned short* __restrict__ Oa) {
  __shared__ __attribute__((aligned(16))) unsigned short Ks[2][64 * 128]; // 32 KB [key][d] swz
  __shared__ __attribute__((aligned(16))) unsigned short Vs[128 * 64];    // 16 KB  [d][key] swz
  __shared__ __attribute__((aligned(16))) unsigned short Ps[4][16 * 64];  //  8 KB  per-wave P swz
  const int t = threadIdx.x, w = t >> 6, lane = t & 63;
  const int quad = lane >> 4, l16 = lane & 15;
  const int bid = blockIdx.x;                 // 512 blocks
  const int bh = (bid & 7) + 8 * (bid >> 7);
  const int p  = (bid >> 3) & 15;             // pair index 0..15
  const int b = bh >> 4, h = bh & 15;
  const unsigned short* Qp = Qa + (size_t)bh * S_ * HD_;
  const unsigned short* Kp = Ka + (size_t)bh * S_ * HD_;
  const unsigned short* Vp = Vt + (size_t)bh * HD_ * S_;
  const float NEGINF = -__builtin_inff();

  for (int part = 0; part < 2; ++part) {
    const int qs = part ? (31 - p) : p;       // 64-row q-subtile index
    const int q0 = qs * 64;
    const int ntmax = qs;                     // k-tiles 0..qs (64 keys each)

    __syncthreads();   // prior part's LDS reads fully done before restage

    // stage K[0]: LDS[row][cb] = K[row][cb ^ ((row&7)<<4)]
#pragma unroll
    for (int j = 0; j < 4; ++j) {
      int o = (t + 256 * j) * 16;
      int row = o >> 8, cb = (o & 255) ^ ((row & 7) << 4);
      gld16((char*)Ks[0] + w * 1024 + j * 4096, (const char*)(Kp + (size_t)row * HD_) + cb);
    }
    // Q fragments: loop-invariant, straight from global (16B/lane)
    bf16x8 qf[4];
#pragma unroll
    for (int kk = 0; kk < 4; ++kk)
      qf[kk] = *(const bf16x8*)(Qp + (size_t)(q0 + w * 16 + l16) * HD_ + kk * 32 + quad * 8);

    float m_i[4], l_i[4];
#pragma unroll
    for (int r = 0; r < 4; ++r) { m_i[r] = NEGINF; l_i[r] = 0.f; }
    f32x4 oacc[8] = {};
    int c = 0;

    for (int nt = 0; nt <= ntmax; ++nt) {
      __syncthreads();   // K[c] resident; drains K prefetch issued last iter

      // early-issue V[nt]: consumed only after softmax (mid barrier). 128B rows, swizzled src.
#pragma unroll
      for (int j = 0; j < 4; ++j) {
        int o = (t + 256 * j) * 16;
        int vrow = o >> 7, vcb = (o & 127) ^ ((vrow & 7) << 4);
        gld16((char*)Vs + w * 1024 + j * 4096,
              (const char*)(Vp + (size_t)vrow * S_ + nt * 64) + vcb);
      }

      // --- S = Q K^T: wave's 16 q-rows x 64 keys (log2 domain)
      f32x4 sacc[4] = {};
      const char* Kc = (const char*)Ks[c];
#pragma unroll
      for (int j = 0; j < 4; ++j) {
        int krow = j * 16 + l16;
        const char* kbase = Kc + krow * 256;
        int ksw = (krow & 7) << 4;
#pragma unroll
        for (int kk = 0; kk < 4; ++kk) {
          bf16x8 kf = lds_frag_b(kbase + ((kk * 64 + quad * 16) ^ ksw));
          sacc[j] = __builtin_amdgcn_mfma_f32_16x16x32_bf16(qf[kk], kf, sacc[j], 0, 0, 0);
        }
      }

      // --- causal mask (diagonal tile only) + online softmax (exp2 domain)
      const bool dotail = (nt == ntmax);
      float rowmax[4], alpha[4], rowsum[4];
#pragma unroll
      for (int r = 0; r < 4; ++r) rowmax[r] = NEGINF;
#pragma unroll
      for (int j = 0; j < 4; ++j) {
        int scol = nt * 64 + j * 16 + l16;
#pragma unroll
        for (int r = 0; r < 4; ++r) {
          float v = sacc[j][r];
          if (dotail && scol > q0 + w * 16 + quad * 4 + r) v = NEGINF;
          sacc[j][r] = v;
          rowmax[r] = fmaxf(rowmax[r], v);
        }
      }
#pragma unroll
      for (int off = 1; off < 16; off <<= 1)
#pragma unroll
        for (int r = 0; r < 4; ++r)
          rowmax[r] = fmaxf(rowmax[r], __shfl_xor(rowmax[r], off));
#pragma unroll
      for (int r = 0; r < 4; ++r) {
        float mnew = fmaxf(m_i[r], rowmax[r]);
        alpha[r] = __builtin_amdgcn_exp2f(m_i[r] - mnew);   // first tile: exp2(-inf)=0
        m_i[r] = mnew;
        rowsum[r] = 0.f;
      }
#pragma unroll
      for (int j = 0; j < 4; ++j)
#pragma unroll
        for (int r = 0; r < 4; ++r) {
          float e = __builtin_amdgcn_exp2f(sacc[j][r] - m_i[r]);  // masked: exp2(-inf)=0
          sacc[j][r] = e;
          rowsum[r] += e;
        }
#pragma unroll
      for (int off = 1; off < 16; off <<= 1)
#pragma unroll
        for (int r = 0; r < 4; ++r)
          rowsum[r] += __shfl_xor(rowsum[r], off);
#pragma unroll
      for (int r = 0; r < 4; ++r) l_i[r] = l_i[r] * alpha[r] + rowsum[r];
#pragma unroll
      for (int f = 0; f < 8; ++f)
#pragma unroll
        for (int r = 0; r < 4; ++r) oacc[f][r] *= alpha[r];

      __syncthreads();   // V[nt] resident (drain covered by QK+softmax work)

      // prefetch K[nt+1] AFTER mid barrier: drained at NEXT top barrier (covered by PV)
      if (nt < ntmax) {
#pragma unroll
        for (int j = 0; j < 4; ++j) {
          int o = (t + 256 * j) * 16;
          int row = o >> 8, cb = (o & 255) ^ ((row & 7) << 4);
          gld16((char*)Ks[c ^ 1] + w * 1024 + j * 4096,
                (const char*)(Kp + (size_t)((nt + 1) * 64 + row) * HD_) + cb);
        }
      }

      // --- P: C-layout regs -> per-wave LDS (bf16, swizzled)
      char* Pw = (char*)&Ps[w][0];
#pragma unroll
      for (int j = 0; j < 4; ++j)
#pragma unroll
        for (int r = 0; r < 4; ++r) {
          int prow = quad * 4 + r;
          *(unsigned short*)(Pw + prow * 128 + ((2 * (j * 16 + l16)) ^ ((prow & 7) << 4))) = f2bf(sacc[j][r]);
        }
      asm volatile("s_waitcnt lgkmcnt(0)" ::: "memory");  // per-wave RAW on Ps

      // --- O += P V  (2 k-steps over 64 keys x 8 d-fragments)
      const char* Vb = (const char*)Vs;
      int psw = (l16 & 7) << 4;
#pragma unroll
      for (int s2 = 0; s2 < 2; ++s2) {
        bf16x8 pf = lds_frag_b(Pw + l16 * 128 + ((s2 * 64 + quad * 16) ^ psw));
#pragma unroll
        for (int f = 0; f < 8; ++f) {
          int vrow = f * 16 + l16;
          bf16x8 vf = lds_frag_b(Vb + vrow * 128 + ((s2 * 64 + quad * 16) ^ ((vrow & 7) << 4)));
          oacc[f] = __builtin_amdgcn_mfma_f32_16x16x32_bf16(pf, vf, oacc[f], 0, 0, 0);
        }
      }
      c ^= 1;
    }

    // epilogue: O / l -> bf16 (B,S,D)
    float invl[4];
#pragma unroll
    for (int r = 0; r < 4; ++r) invl[r] = 1.f / l_i[r];
#pragma unroll
    for (int f = 0; f < 8; ++f)
#pragma unroll
      for (int r = 0; r < 4; ++r) {
        int srow = q0 + w * 16 + quad * 4 + r;
        int d = f * 16 + l16;
        Oa[((size_t)(b * S_ + srow)) * D_ + h * HD_ + d] = f2bf(oacc[f][r] * invl[r]);
      }
  }
}

// ----------------------------------------------------------------
extern "C" void kernel_launch(void* const* d_in, const int* in_sizes, int n_in,
                              void* d_out, int out_size, void* d_ws, size_t ws_size,
                              hipStream_t stream) {
  const float* x    = (const float*)d_in[0];
  const float* wq_w = (const float*)d_in[1];
  const float* wq_b = (const float*)d_in[2];
  const float* wk_w = (const float*)d_in[3];
  const float* wk_b = (const float*)d_in[4];
  const float* wv_w = (const float*)d_in[5];
  const float* wv_b = (const float*)d_in[6];
  const float* wo_w = (const float*)d_in[7];
  const float* wo_b = (const float*)d_in[8];
  const float* fc   = (const float*)d_in[9];
  const float* fs   = (const float*)d_in[10];

  float* out = (float*)d_out;
  const size_t BSD = (size_t)B_ * S_ * D_;   // 8388608
  float* k_out = out + BSD;
  float* v_out = out + 2 * BSD;

  // workspace layout
  char* ws = (char*)d_ws;
  unsigned short* xb   = (unsigned short*)(ws);              // x bf16          16.78 MB
  unsigned short* wqb  = (unsigned short*)(ws + 16777216);   // wq bf16          8.39 MB (wq|wk|wv contiguous)
  unsigned short* wkb  = (unsigned short*)(ws + 25165824);
  unsigned short* wvb  = (unsigned short*)(ws + 33554432);
  unsigned short* wob  = (unsigned short*)(ws + 41943040);
  float*          Kbuf = (float*)(ws + 50331648);            // K fp32 (B,S,D)  33.55 MB
  unsigned short* Qat  = (unsigned short*)(ws + 83886080);   // Q roped bf16 (B,H,S,HD), pre-scaled
  unsigned short* Kat  = (unsigned short*)(ws + 100663296);  // K roped bf16 (B,H,S,HD)
  unsigned short* Vt   = (unsigned short*)(ws + 117440512);  // V bf16 (B,H,HD,S)
  unsigned short* Ab   = (unsigned short*)(ws + 134217728);  // attn out bf16 (B,S,D)

  // fp32 Q intermediate borrows d_out (overwritten by final out-projection)
  float* Qbuf = out;

  cvt_all<<<24576, 256, 0, stream>>>(x, wq_w, wk_w, wv_w, wo_w, xb, wqb, wkb, wvb, wob);

  // fused QKV GEMM, 256x256 m201 geometry: 384 blocks (16 x 24), 16 MFMA/phase.
  gemm256_qkv<<<dim3(384), 512, 0, stream>>>(xb, wqb, wq_b, wk_b, wv_b,
                                             Qbuf, Kbuf, v_out);

  // fused RoPE + V-transpose: one launch (16384 rope blocks + 4096 vtrans blocks)
  rope_vtrans<<<20480, 256, 0, stream>>>(Qbuf, Kbuf, fc, fs, Qat, Kat, k_out, v_out, Vt);

  attn_kernel<<<512, 256, 0, stream>>>(Qat, Kat, Vt, Ab);

  // output projection: proven 256x128 8-phase, 256 blocks = 1 exact CU round
  gemm8p<<<dim3(256), 512, 0, stream>>>(Ab, wob, wo_b, out, 16);
}

// Round 10
// 451.051 us; speedup vs baseline: 1.0250x; 1.0063x over previous
//
#include <hip/hip_runtime.h>

// Problem constants
#define B_  2
#define S_  2048
#define D_  2048
#define H_  16
#define HD_ 128

// 1/sqrt(128) * log2(e): fold softmax scale AND exp->exp2 conversion into Q
#define QSCALE 0.1275174319003887f

typedef __attribute__((ext_vector_type(4))) float  f32x4;
typedef __attribute__((ext_vector_type(8))) short  short8;
typedef __attribute__((ext_vector_type(8))) __bf16 bf16x8;
typedef __attribute__((ext_vector_type(4))) float  floatv4;
typedef __attribute__((ext_vector_type(4))) unsigned short ushortv4;

// fp32 -> bf16 bits, round-to-nearest-even
__device__ inline unsigned short f2bf(float f) {
  unsigned int u = __builtin_bit_cast(unsigned int, f);
  u += 0x7fffu + ((u >> 16) & 1u);
  return (unsigned short)(u >> 16);
}

// async global->LDS, 16B per lane. lds must be wave-uniform base; data lands at base + lane*16.
__device__ inline void gld16(void* lds, const void* g) {
  __builtin_amdgcn_global_load_lds(
      (const __attribute__((address_space(1))) unsigned int*)g,
      (__attribute__((address_space(3))) unsigned int*)lds, 16, 0, 0);
}

__device__ inline bf16x8 lds_frag_b(const void* p) {
  return __builtin_bit_cast(bf16x8, *(const short8*)p);
}

// ---------------------------------------------------------------- fused converts (x + 4 weights)
__global__ void cvt_all(const float* __restrict__ x,
                        const float* __restrict__ w0, const float* __restrict__ w1,
                        const float* __restrict__ w2, const float* __restrict__ w3,
                        unsigned short* __restrict__ xb,
                        unsigned short* __restrict__ wb0, unsigned short* __restrict__ wb1,
                        unsigned short* __restrict__ wb2, unsigned short* __restrict__ wb3) {
  int i = blockIdx.x * 256 + threadIdx.x;   // quad index, total 6291456
  const float* s; unsigned short* d; int off;
  if (i < 2097152) { s = x; d = xb; off = i; }
  else {
    int j = i - 2097152;
    int r = j >> 20; off = j & 1048575;
    s = (r == 0) ? w0 : (r == 1) ? w1 : (r == 2) ? w2 : w3;
    d = (r == 0) ? wb0 : (r == 1) ? wb1 : (r == 2) ? wb2 : wb3;
  }
  floatv4 v = ((const floatv4*)s)[off];
  ushortv4 o;
  o.x = f2bf(v.x); o.y = f2bf(v.y); o.z = f2bf(v.z); o.w = f2bf(v.w);
  ((ushortv4*)d)[off] = o;
}

// ---------------------------------------------------------------- 8-phase GEMM (NT), BM=256 BN=128 BK=64, 8 waves.
// PROVEN schedule (R3/R7/R8: 116-122 us, MfmaUtil 36-39%). Experiments rejected by A/B:
//   - 4-phase merge (R5/R6): 139-161 us (m196-class: coarse split w/o fine interleave)
//   - 256x256 tile (R9): 143.9 us, util 30% (2x work/block needs 2x util to break even; fell instead)
// Counted vmcnt: vmcnt(4)@P4 (buf1 tile landed), vmcnt(6)@P8 (buf0 tile landed). Never 0 in-loop.
// T2 swizzle (row&7)<<4; inverse-swizzled global src, linear LDS dest (rule #21).
// MODE 0: plain fp32 C (N=2048).
// MODE 1: QKV - coalesced fp32 stores: Q->CQ (B,S,D), K->CK (B,S,D), V->v_out (B,H,S,HD) direct.
template<int MI0, int NJ0>
__device__ inline void quad_mm(f32x4 (&acc)[4][4], const bf16x8 (&af)[2][2], const bf16x8 (&bf)[2][2]) {
#pragma unroll
  for (int mi = 0; mi < 2; ++mi)
#pragma unroll
    for (int nj = 0; nj < 2; ++nj)
#pragma unroll
      for (int ks = 0; ks < 2; ++ks)
        acc[MI0 + mi][NJ0 + nj] =
            __builtin_amdgcn_mfma_f32_16x16x32_bf16(af[mi][ks], bf[nj][ks], acc[MI0 + mi][NJ0 + nj], 0, 0, 0);
}

// stage one 8KB chunk (64 rows x 128B): global row stride 4096B, per-thread offset thrOff pre-swizzled
__device__ inline void stage(char* ldsbuf, int chunk, const char* gtile, int w, long thrOff) {
  gld16(ldsbuf + chunk * 8192 + w * 1024, gtile + (long)chunk * 64 * 4096 + thrOff);
}

#define RDF(dst, buf, baserow)                                                          \
  do {                                                                                  \
    int _r0 = (baserow);                                                                \
    _Pragma("unroll") for (int _ii = 0; _ii < 2; ++_ii) {                               \
      int _row = _r0 + _ii * 16;                                                        \
      _Pragma("unroll") for (int _ks = 0; _ks < 2; ++_ks)                               \
          dst[_ii][_ks] = lds_frag_b((buf) + _row * 128 + ((_ks * 64 + quad * 16) ^ xsw)); \
    }                                                                                   \
  } while (0)

#define GBAR() __builtin_amdgcn_s_barrier()
#define LGK0()                                                 \
  do {                                                         \
    asm volatile("s_waitcnt lgkmcnt(0)" ::: "memory");         \
    __builtin_amdgcn_sched_barrier(0);                         \
  } while (0)

template<int MODE>
__global__ __launch_bounds__(512, 1)
void gemm8p(const unsigned short* __restrict__ A,
            const unsigned short* __restrict__ W,
            const float* __restrict__ b0, const float* __restrict__ b1, const float* __restrict__ b2,
            float* __restrict__ CQ,      // MODE0: C. MODE1: Q fp32 (B,S,D)
            float* __restrict__ CK,      // MODE1: K fp32 (B,S,D)
            float* __restrict__ v_out,   // MODE1: V fp32 (B,H,S,HD)
            int nbx) {
  __shared__ __attribute__((aligned(16))) char smem[98304];  // As0|As1 (32K each), Bs0|Bs1 (16K each)
  char* As0 = smem;
  char* As1 = smem + 32768;
  char* Bs0 = smem + 65536;
  char* Bs1 = smem + 81920;

  const int t = threadIdx.x, w = t >> 6, lane = t & 63;
  const int quad = lane >> 4, l16 = lane & 15;
  const int wm = (w >> 1) * 64, wn = (w & 1) * 64;   // 4M x 2N waves, 64x64 per wave
  const int xsw = (l16 & 7) << 4;

  // XCD-bijective block decode (grid divisible by 8): contiguous wg chunk per XCD
  const int nwg = gridDim.x, q8 = nwg >> 3;
  const int wg = ((int)blockIdx.x & 7) * q8 + ((int)blockIdx.x >> 3);
  const int by = wg / nbx, bx = wg % nbx;
  const int m0 = by * 256, n0 = bx * 128;

  const char* Agl = (const char*)A + (size_t)m0 * 4096;   // row stride K*2 = 4096 B
  const char* Wgl = (const char*)W + (size_t)n0 * 4096;
  const int sr = t >> 3;
  const long thrOff = (long)sr * 4096 + (((t & 7) * 16) ^ ((sr & 7) << 4));  // inverse-swizzled src

  // prologue: prime tiles 0 (buf0) and 1 (buf1); oldest 6 = tile0
#pragma unroll
  for (int c = 0; c < 4; ++c) stage(As0, c, Agl, w, thrOff);
#pragma unroll
  for (int c = 0; c < 2; ++c) stage(Bs0, c, Wgl, w, thrOff);
#pragma unroll
  for (int c = 0; c < 4; ++c) stage(As1, c, Agl + 128, w, thrOff);
#pragma unroll
  for (int c = 0; c < 2; ++c) stage(Bs1, c, Wgl + 128, w, thrOff);
  asm volatile("s_waitcnt vmcnt(6)" ::: "memory");
  GBAR();

  f32x4 acc[4][4] = {};

  for (int it = 0; it < 16; ++it) {
    int s0 = 2 * it + 2; if (s0 >= 32) s0 -= 2;   // tail: benign identical restage
    int s1 = 2 * it + 3; if (s1 >= 32) s1 -= 2;
    const char* As0g = Agl + (long)s0 * 128;
    const char* Bs0g = Wgl + (long)s0 * 128;
    const char* As1g = Agl + (long)s1 * 128;
    const char* Bs1g = Wgl + (long)s1 * 128;
    bf16x8 a01[2][2], a23[2][2], b01[2][2], b23[2][2];

    // ---- P1: rd A01,B01 (buf0)                      | mfma Q(0,0)
    RDF(a01, As0, wm + l16);
    RDF(b01, Bs0, wn + l16);
    GBAR(); LGK0();
    __builtin_amdgcn_s_setprio(1); quad_mm<0, 0>(acc, a01, b01); __builtin_amdgcn_s_setprio(0);
    GBAR();
    // ---- P2: rd A23 (buf0)                          | mfma Q(2,0)
    RDF(a23, As0, wm + 32 + l16);
    GBAR(); LGK0();
    __builtin_amdgcn_s_setprio(1); quad_mm<2, 0>(acc, a23, b01); __builtin_amdgcn_s_setprio(0);
    GBAR();
    // ---- P3: rd B23 (buf0); stage buf0.A01 (free since P2) | mfma Q(0,2)
    RDF(b23, Bs0, wn + 32 + l16);
    stage(As0, 0, As0g, w, thrOff); stage(As0, 1, As0g, w, thrOff);
    GBAR(); LGK0();
    __builtin_amdgcn_s_setprio(1); quad_mm<0, 2>(acc, a01, b23); __builtin_amdgcn_s_setprio(0);
    GBAR();
    // ---- P4: stage buf0.A23                         | mfma Q(2,2) | vmcnt(4): buf1 tile landed
    stage(As0, 2, As0g, w, thrOff); stage(As0, 3, As0g, w, thrOff);
    GBAR(); LGK0();
    __builtin_amdgcn_s_setprio(1); quad_mm<2, 2>(acc, a23, b23); __builtin_amdgcn_s_setprio(0);
    asm volatile("s_waitcnt vmcnt(4)" ::: "memory");
    GBAR();
    // ---- P5: rd A01,B01 (buf1); stage buf0.B (free since P3) | mfma Q(0,0)
    RDF(a01, As1, wm + l16);
    RDF(b01, Bs1, wn + l16);
    stage(Bs0, 0, Bs0g, w, thrOff); stage(Bs0, 1, Bs0g, w, thrOff);
    GBAR(); LGK0();
    __builtin_amdgcn_s_setprio(1); quad_mm<0, 0>(acc, a01, b01); __builtin_amdgcn_s_setprio(0);
    GBAR();
    // ---- P6: rd A23 (buf1)                          | mfma Q(2,0)
    RDF(a23, As1, wm + 32 + l16);
    GBAR(); LGK0();
    __builtin_amdgcn_s_setprio(1); quad_mm<2, 0>(acc, a23, b01); __builtin_amdgcn_s_setprio(0);
    GBAR();
    // ---- P7: rd B23 (buf1); stage buf1.A01 (free since P6) | mfma Q(0,2)
    RDF(b23, Bs1, wn + 32 + l16);
    stage(As1, 0, As1g, w, thrOff); stage(As1, 1, As1g, w, thrOff);
    GBAR(); LGK0();
    __builtin_amdgcn_s_setprio(1); quad_mm<0, 2>(acc, a01, b23); __builtin_amdgcn_s_setprio(0);
    GBAR();
    // ---- P8: stage buf1.A23 + buf1.B (free since P7) | mfma Q(2,2) | vmcnt(6): buf0 tile landed
    stage(As1, 2, As1g, w, thrOff); stage(As1, 3, As1g, w, thrOff);
    stage(Bs1, 0, Bs1g, w, thrOff); stage(Bs1, 1, Bs1g, w, thrOff);
    GBAR(); LGK0();
    __builtin_amdgcn_s_setprio(1); quad_mm<2, 2>(acc, a23, b23); __builtin_amdgcn_s_setprio(0);
    asm volatile("s_waitcnt vmcnt(6)" ::: "memory");
    GBAR();
  }

  // drain tail restages before epilogue
  asm volatile("s_waitcnt vmcnt(0)" ::: "memory");

  // epilogue: C/D layout col=l16, row=quad*4+r. All stores fp32, 64B-per-16-lane coalesced.
  if constexpr (MODE == 1) {
#pragma unroll
    for (int nj = 0; nj < 4; ++nj) {
      int col = n0 + wn + nj * 16 + l16;            // 0..6143
      int sel = col >> 11;                          // 0=Q 1=K 2=V (uniform across wave)
      int cc  = col & 2047;
      const float* bp = (sel == 0) ? b0 : (sel == 1) ? b1 : b2;
      float bv = bp[cc];
#pragma unroll
      for (int mi = 0; mi < 4; ++mi)
#pragma unroll
        for (int r = 0; r < 4; ++r) {
          int row = m0 + wm + mi * 16 + quad * 4 + r;
          float v = acc[mi][nj][r] + bv;
          if (sel == 0) {
            CQ[(size_t)row * 2048 + cc] = v;
          } else if (sel == 1) {
            CK[(size_t)row * 2048 + cc] = v;
          } else {
            int s = row & 2047, bb = row >> 11;
            int hh = cc >> 7, d = cc & 127;
            v_out[((size_t)(bb * H_ + hh) * S_ + s) * HD_ + d] = v;
          }
        }
    }
  } else {
#pragma unroll
    for (int nj = 0; nj < 4; ++nj) {
      int col = n0 + wn + nj * 16 + l16;
      float bv = b0[col];
#pragma unroll
      for (int mi = 0; mi < 4; ++mi)
#pragma unroll
        for (int r = 0; r < 4; ++r) {
          int row = m0 + wm + mi * 16 + quad * 4 + r;
          CQ[(size_t)row * 2048 + col] = acc[mi][nj][r] + bv;
        }
    }
  }
}

// ---------------------------------------------------------------- RoPE: Q,K (B,S,D) fp32 -> (B,H,S,HD)
// Qa gets scale*log2e folded in (softmax runs in exp2 domain); Ka/k_out are unscaled.
// Kept SEPARATE from vtrans: R6 vs R9 single-variable A/B showed the fused version ~10us slower.
__global__ void rope_kernel(const float* __restrict__ Qbuf,
                            const float* __restrict__ Kbuf,
                            const float* __restrict__ fc,
                            const float* __restrict__ fs,
                            unsigned short* __restrict__ Qa,
                            unsigned short* __restrict__ Ka,
                            float* __restrict__ k_out) {
  int idx = blockIdx.x * 256 + threadIdx.x;   // (b:1, s:11, h:4, i:6)
  int i = idx & 63;
  int h = (idx >> 6) & (H_ - 1);
  int s = (idx >> 10) & (S_ - 1);
  int b = idx >> 21;
  size_t src = ((size_t)(b * S_ + s)) * D_ + h * HD_ + 2 * i;
  float2 q = *(const float2*)(Qbuf + src);
  float2 k = *(const float2*)(Kbuf + src);
  float c = fc[s * 64 + i], sn = fs[s * 64 + i];
  float qor = q.x * c - q.y * sn, qoi = q.x * sn + q.y * c;
  float kor = k.x * c - k.y * sn, koi = k.x * sn + k.y * c;
  size_t dst = ((size_t)((b * H_ + h) * S_ + s)) * HD_ + 2 * i;
  *(unsigned int*)(Qa + dst) = (unsigned int)f2bf(qor * QSCALE) | ((unsigned int)f2bf(qoi * QSCALE) << 16);
  *(unsigned int*)(Ka + dst) = (unsigned int)f2bf(kor) | ((unsigned int)f2bf(koi) << 16);
  *(float2*)(k_out + dst) = make_float2(kor, koi);
}

// ---------------------------------------------------------------- V: v_out (B,H,S,HD) fp32 -> Vt (B,H,HD,S) bf16
__global__ void vtrans_kernel(const float* __restrict__ Vsrc,
                              unsigned short* __restrict__ Vt) {
  __shared__ float tile[64][33];
  int t = threadIdx.x;
  int s0 = blockIdx.x * 64, d0 = blockIdx.y * 32, bh = blockIdx.z;
#pragma unroll
  for (int rr = 0; rr < 8; ++rr) {
    int sl = rr * 8 + (t >> 5), dl = t & 31;
    tile[sl][dl] = Vsrc[((size_t)(bh * S_ + s0 + sl)) * HD_ + d0 + dl];
  }
  __syncthreads();
#pragma unroll
  for (int rr = 0; rr < 8; ++rr) {
    int dl = rr * 4 + (t >> 6), sl = t & 63;
    Vt[((size_t)(bh * HD_ + d0 + dl)) * S_ + s0 + sl] = f2bf(tile[sl][dl]);
  }
}

// ---------------------------------------------------------------- causal flash attention
// 64 q-rows/block (16/wave), paired subtiles {qs, 31-qs} per block for perfect causal balance
// (33 k-tiles each). 512 blocks -> 2 blocks/CU. Ks/Vs/Ps XOR-swizzled ((row&7)<<4).
// Plain version is the measured best: T13 (+~30us, R7) and setprio (+~30us, R8) both rejected
// (lockstep 4-wave block + 2 blocks/CU: priority starves the co-resident block).
__global__ __launch_bounds__(256, 2)
void attn_kernel(const unsigned short* __restrict__ Qa,
                 const unsigned short* __restrict__ Ka,
                 const unsigned short* __restrict__ Vt,
                 unsigned short* __restrict__ Oa) {
  __shared__ __attribute__((aligned(16))) unsigned short Ks[2][64 * 128]; // 32 KB [key][d] swz
  __shared__ __attribute__((aligned(16))) unsigned short Vs[128 * 64];    // 16 KB  [d][key] swz
  __shared__ __attribute__((aligned(16))) unsigned short Ps[4][16 * 64];  //  8 KB  per-wave P swz
  const int t = threadIdx.x, w = t >> 6, lane = t & 63;
  const int quad = lane >> 4, l16 = lane & 15;
  const int bid = blockIdx.x;                 // 512 blocks
  const int bh = (bid & 7) + 8 * (bid >> 7);
  const int p  = (bid >> 3) & 15;             // pair index 0..15
  const int b = bh >> 4, h = bh & 15;
  const unsigned short* Qp = Qa + (size_t)bh * S_ * HD_;
  const unsigned short* Kp = Ka + (size_t)bh * S_ * HD_;
  const unsigned short* Vp = Vt + (size_t)bh * HD_ * S_;
  const float NEGINF = -__builtin_inff();

  for (int part = 0; part < 2; ++part) {
    const int qs = part ? (31 - p) : p;       // 64-row q-subtile index
    const int q0 = qs * 64;
    const int ntmax = qs;                     // k-tiles 0..qs (64 keys each)

    __syncthreads();   // prior part's LDS reads fully done before restage

    // stage K[0]: LDS[row][cb] = K[row][cb ^ ((row&7)<<4)]
#pragma unroll
    for (int j = 0; j < 4; ++j) {
      int o = (t + 256 * j) * 16;
      int row = o >> 8, cb = (o & 255) ^ ((row & 7) << 4);
      gld16((char*)Ks[0] + w * 1024 + j * 4096, (const char*)(Kp + (size_t)row * HD_) + cb);
    }
    // Q fragments: loop-invariant, straight from global (16B/lane)
    bf16x8 qf[4];
#pragma unroll
    for (int kk = 0; kk < 4; ++kk)
      qf[kk] = *(const bf16x8*)(Qp + (size_t)(q0 + w * 16 + l16) * HD_ + kk * 32 + quad * 8);

    float m_i[4], l_i[4];
#pragma unroll
    for (int r = 0; r < 4; ++r) { m_i[r] = NEGINF; l_i[r] = 0.f; }
    f32x4 oacc[8] = {};
    int c = 0;

    for (int nt = 0; nt <= ntmax; ++nt) {
      __syncthreads();   // K[c] resident; drains K prefetch issued last iter

      // early-issue V[nt]: consumed only after softmax (mid barrier). 128B rows, swizzled src.
#pragma unroll
      for (int j = 0; j < 4; ++j) {
        int o = (t + 256 * j) * 16;
        int vrow = o >> 7, vcb = (o & 127) ^ ((vrow & 7) << 4);
        gld16((char*)Vs + w * 1024 + j * 4096,
              (const char*)(Vp + (size_t)vrow * S_ + nt * 64) + vcb);
      }

      // --- S = Q K^T: wave's 16 q-rows x 64 keys (log2 domain)
      f32x4 sacc[4] = {};
      const char* Kc = (const char*)Ks[c];
#pragma unroll
      for (int j = 0; j < 4; ++j) {
        int krow = j * 16 + l16;
        const char* kbase = Kc + krow * 256;
        int ksw = (krow & 7) << 4;
#pragma unroll
        for (int kk = 0; kk < 4; ++kk) {
          bf16x8 kf = lds_frag_b(kbase + ((kk * 64 + quad * 16) ^ ksw));
          sacc[j] = __builtin_amdgcn_mfma_f32_16x16x32_bf16(qf[kk], kf, sacc[j], 0, 0, 0);
        }
      }

      // --- causal mask (diagonal tile only) + online softmax (exp2 domain)
      const bool dotail = (nt == ntmax);
      float rowmax[4], alpha[4], rowsum[4];
#pragma unroll
      for (int r = 0; r < 4; ++r) rowmax[r] = NEGINF;
#pragma unroll
      for (int j = 0; j < 4; ++j) {
        int scol = nt * 64 + j * 16 + l16;
#pragma unroll
        for (int r = 0; r < 4; ++r) {
          float v = sacc[j][r];
          if (dotail && scol > q0 + w * 16 + quad * 4 + r) v = NEGINF;
          sacc[j][r] = v;
          rowmax[r] = fmaxf(rowmax[r], v);
        }
      }
#pragma unroll
      for (int off = 1; off < 16; off <<= 1)
#pragma unroll
        for (int r = 0; r < 4; ++r)
          rowmax[r] = fmaxf(rowmax[r], __shfl_xor(rowmax[r], off));
#pragma unroll
      for (int r = 0; r < 4; ++r) {
        float mnew = fmaxf(m_i[r], rowmax[r]);
        alpha[r] = __builtin_amdgcn_exp2f(m_i[r] - mnew);   // first tile: exp2(-inf)=0
        m_i[r] = mnew;
        rowsum[r] = 0.f;
      }
#pragma unroll
      for (int j = 0; j < 4; ++j)
#pragma unroll
        for (int r = 0; r < 4; ++r) {
          float e = __builtin_amdgcn_exp2f(sacc[j][r] - m_i[r]);  // masked: exp2(-inf)=0
          sacc[j][r] = e;
          rowsum[r] += e;
        }
#pragma unroll
      for (int off = 1; off < 16; off <<= 1)
#pragma unroll
        for (int r = 0; r < 4; ++r)
          rowsum[r] += __shfl_xor(rowsum[r], off);
#pragma unroll
      for (int r = 0; r < 4; ++r) l_i[r] = l_i[r] * alpha[r] + rowsum[r];
#pragma unroll
      for (int f = 0; f < 8; ++f)
#pragma unroll
        for (int r = 0; r < 4; ++r) oacc[f][r] *= alpha[r];

      __syncthreads();   // V[nt] resident (drain covered by QK+softmax work)

      // prefetch K[nt+1] AFTER mid barrier: drained at NEXT top barrier (covered by PV)
      if (nt < ntmax) {
#pragma unroll
        for (int j = 0; j < 4; ++j) {
          int o = (t + 256 * j) * 16;
          int row = o >> 8, cb = (o & 255) ^ ((row & 7) << 4);
          gld16((char*)Ks[c ^ 1] + w * 1024 + j * 4096,
                (const char*)(Kp + (size_t)((nt + 1) * 64 + row) * HD_) + cb);
        }
      }

      // --- P: C-layout regs -> per-wave LDS (bf16, swizzled)
      char* Pw = (char*)&Ps[w][0];
#pragma unroll
      for (int j = 0; j < 4; ++j)
#pragma unroll
        for (int r = 0; r < 4; ++r) {
          int prow = quad * 4 + r;
          *(unsigned short*)(Pw + prow * 128 + ((2 * (j * 16 + l16)) ^ ((prow & 7) << 4))) = f2bf(sacc[j][r]);
        }
      asm volatile("s_waitcnt lgkmcnt(0)" ::: "memory");  // per-wave RAW on Ps

      // --- O += P V  (2 k-steps over 64 keys x 8 d-fragments)
      const char* Vb = (const char*)Vs;
      int psw = (l16 & 7) << 4;
#pragma unroll
      for (int s2 = 0; s2 < 2; ++s2) {
        bf16x8 pf = lds_frag_b(Pw + l16 * 128 + ((s2 * 64 + quad * 16) ^ psw));
#pragma unroll
        for (int f = 0; f < 8; ++f) {
          int vrow = f * 16 + l16;
          bf16x8 vf = lds_frag_b(Vb + vrow * 128 + ((s2 * 64 + quad * 16) ^ ((vrow & 7) << 4)));
          oacc[f] = __builtin_amdgcn_mfma_f32_16x16x32_bf16(pf, vf, oacc[f], 0, 0, 0);
        }
      }
      c ^= 1;
    }

    // epilogue: O / l -> bf16 (B,S,D)
    float invl[4];
#pragma unroll
    for (int r = 0; r < 4; ++r) invl[r] = 1.f / l_i[r];
#pragma unroll
    for (int f = 0; f < 8; ++f)
#pragma unroll
      for (int r = 0; r < 4; ++r) {
        int srow = q0 + w * 16 + quad * 4 + r;
        int d = f * 16 + l16;
        Oa[((size_t)(b * S_ + srow)) * D_ + h * HD_ + d] = f2bf(oacc[f][r] * invl[r]);
      }
  }
}

// ----------------------------------------------------------------
extern "C" void kernel_launch(void* const* d_in, const int* in_sizes, int n_in,
                              void* d_out, int out_size, void* d_ws, size_t ws_size,
                              hipStream_t stream) {
  const float* x    = (const float*)d_in[0];
  const float* wq_w = (const float*)d_in[1];
  const float* wq_b = (const float*)d_in[2];
  const float* wk_w = (const float*)d_in[3];
  const float* wk_b = (const float*)d_in[4];
  const float* wv_w = (const float*)d_in[5];
  const float* wv_b = (const float*)d_in[6];
  const float* wo_w = (const float*)d_in[7];
  const float* wo_b = (const float*)d_in[8];
  const float* fc   = (const float*)d_in[9];
  const float* fs   = (const float*)d_in[10];

  float* out = (float*)d_out;
  const size_t BSD = (size_t)B_ * S_ * D_;   // 8388608
  float* k_out = out + BSD;
  float* v_out = out + 2 * BSD;

  // workspace layout
  char* ws = (char*)d_ws;
  unsigned short* xb   = (unsigned short*)(ws);              // x bf16          16.78 MB
  unsigned short* wqb  = (unsigned short*)(ws + 16777216);   // wq bf16          8.39 MB (wq|wk|wv contiguous)
  unsigned short* wkb  = (unsigned short*)(ws + 25165824);
  unsigned short* wvb  = (unsigned short*)(ws + 33554432);
  unsigned short* wob  = (unsigned short*)(ws + 41943040);
  float*          Kbuf = (float*)(ws + 50331648);            // K fp32 (B,S,D)  33.55 MB
  unsigned short* Qat  = (unsigned short*)(ws + 83886080);   // Q roped bf16 (B,H,S,HD), pre-scaled
  unsigned short* Kat  = (unsigned short*)(ws + 100663296);  // K roped bf16 (B,H,S,HD)
  unsigned short* Vt   = (unsigned short*)(ws + 117440512);  // V bf16 (B,H,HD,S)
  unsigned short* Ab   = (unsigned short*)(ws + 134217728);  // attn out bf16 (B,S,D)

  // fp32 Q intermediate borrows d_out (overwritten by final out-projection)
  float* Qbuf = out;

  cvt_all<<<24576, 256, 0, stream>>>(x, wq_w, wk_w, wv_w, wo_w, xb, wqb, wkb, wvb, wob);

  // fused QKV GEMM (N=6144): 768 blocks = 3 exact CU rounds.
  // Q->Qbuf fp32, K->Kbuf fp32 (coalesced (B,S,D)); V->v_out fp32 (B,H,S,HD) direct.
  gemm8p<1><<<dim3(768), 512, 0, stream>>>(xb, wqb, wq_b, wk_b, wv_b,
                                           Qbuf, Kbuf, v_out, 48);

  rope_kernel<<<16384, 256, 0, stream>>>(Qbuf, Kbuf, fc, fs, Qat, Kat, k_out);
  vtrans_kernel<<<dim3(32, 4, 32), 256, 0, stream>>>(v_out, Vt);
  attn_kernel<<<512, 256, 0, stream>>>(Qat, Kat, Vt, Ab);

  // output projection: 256 blocks = 1 exact CU round
  gemm8p<0><<<dim3(256), 512, 0, stream>>>(Ab, wob, wo_b, nullptr, nullptr,
                                           out, nullptr, nullptr, 16);
}